// Round 12
// baseline (1752.134 us; speedup 1.0000x reference)
//
#include <hip/hip_runtime.h>
#include <hip/hip_bf16.h>

#define TT 32
#define DD 128
#define HH 256
#define VV 32000
#define ZZ 256
#define NTL 50            // n-slabs for V-GEMM (50 x 640 = 32000)
#define HOFP 258          // hof/zl row pitch in f32 (256+2; 4*258%32=8 -> conflict-free g-spread)

typedef __attribute__((ext_vector_type(8))) short bf16x8;
typedef __attribute__((ext_vector_type(4))) float f32x4;
typedef __attribute__((ext_vector_type(8))) _Float16 f16x8;

static __device__ inline unsigned short f2bf(float x) {
    __hip_bfloat16 h = __float2bfloat16(x);
    return *(unsigned short*)&h;
}

// ---------------- edges canonicalizer (bool-vs-int32 layout detect) ----------------
__global__ void edge_canon_k(const unsigned char* __restrict__ eb,
                             unsigned char* __restrict__ canon)
{
    __shared__ int flag;
    if (threadIdx.x == 0) flag = 0;
    __syncthreads();
    int acc = 0;
    for (int i = threadIdx.x; i < TT * DD; i += 256)
        if (i & 3) acc |= eb[i];
    if (acc) atomicOr(&flag, 1);
    __syncthreads();
    const bool is_i32 = (flag == 0);
    for (int i = threadIdx.x; i < TT * DD; i += 256)
        canon[i] = is_i32 ? eb[4 * (size_t)i] : eb[i];
}

// ---------------- pack f32 [nrow16*16][256] -> fragment-linear bf16 (W_out) ----------------
__global__ __launch_bounds__(256) void pack_frag(
    const float* __restrict__ src, __hip_bfloat16* __restrict__ dst, int nchunks_total)
{
    int i = blockIdx.x * 256 + threadIdx.x;
    if (i >= nchunks_total) return;
    int lane = i & 63, ks = (i >> 6) & 7, j = i >> 9;
    int g = lane >> 4, c = lane & 15;
    const float* s = src + (size_t)(j * 16 + c) * HH + ks * 32 + g * 8;
    float4 v0 = *(const float4*)s;
    float4 v1 = *(const float4*)(s + 4);
    bf16x8 o;
    o[0] = (short)f2bf(v0.x); o[1] = (short)f2bf(v0.y);
    o[2] = (short)f2bf(v0.z); o[3] = (short)f2bf(v0.w);
    o[4] = (short)f2bf(v1.x); o[5] = (short)f2bf(v1.y);
    o[6] = (short)f2bf(v1.z); o[7] = (short)f2bf(v1.w);
    *(bf16x8*)(dst + (size_t)i * 8) = o;
}

// ---------------- pack 4 Wih matrices -> fragment-linear bf16, slot = blockIdx.y ----------------
__global__ __launch_bounds__(256) void pack_frag4(
    const float* __restrict__ s0, const float* __restrict__ s1,
    const float* __restrict__ s2, const float* __restrict__ s3,
    __hip_bfloat16* __restrict__ dst)
{
    int i = blockIdx.x * 256 + threadIdx.x;
    if (i >= 24576) return;
    int slot = blockIdx.y;
    const float* src = (slot == 0) ? s0 : (slot == 1) ? s1 : (slot == 2) ? s2 : s3;
    __hip_bfloat16* d = dst + (size_t)slot * 196608;
    int lane = i & 63, ks = (i >> 6) & 7, j = i >> 9;
    int g = lane >> 4, c = lane & 15;
    const float* s = src + (size_t)(j * 16 + c) * HH + ks * 32 + g * 8;
    float4 v0 = *(const float4*)s;
    float4 v1 = *(const float4*)(s + 4);
    bf16x8 o;
    o[0] = (short)f2bf(v0.x); o[1] = (short)f2bf(v0.y);
    o[2] = (short)f2bf(v0.z); o[3] = (short)f2bf(v0.w);
    o[4] = (short)f2bf(v1.x); o[5] = (short)f2bf(v1.y);
    o[6] = (short)f2bf(v1.z); o[7] = (short)f2bf(v1.w);
    *(bf16x8*)(d + (size_t)i * 8) = o;
}

// ---------------- pack 4 Whh matrices -> rnn B-frag f16, slot = blockIdx.y ----------------
// chunk = ((j8*6 + tt)*8 + ks), lane=(g,c): holds W[gt*256 + j8*32 + jg2*16 + c][ks*32+g*8..+8]
// where tt = jg2*3 + gt.
__global__ __launch_bounds__(256) void pack_wrnn4(
    const float* __restrict__ s0, const float* __restrict__ s1,
    const float* __restrict__ s2, const float* __restrict__ s3,
    _Float16* __restrict__ dst)
{
    int i = blockIdx.x * 256 + threadIdx.x;
    if (i >= 24576) return;
    int slot = blockIdx.y;
    const float* src = (slot == 0) ? s0 : (slot == 1) ? s1 : (slot == 2) ? s2 : s3;
    _Float16* d = dst + (size_t)slot * 196608;
    int lane = i & 63;
    int t2 = i >> 6;
    int ks = t2 & 7;
    int t3 = t2 >> 3;
    int tt = t3 % 6;
    int j8 = t3 / 6;
    int g = lane >> 4, c = lane & 15;
    int jg2 = tt / 3, gt = tt % 3;
    int srow = gt * 256 + j8 * 32 + jg2 * 16 + c;
    int scol = ks * 32 + g * 8;
    const float* s = src + (size_t)srow * HH + scol;
    float4 v0 = *(const float4*)s;
    float4 v1 = *(const float4*)(s + 4);
    f16x8 o;
    o[0] = (_Float16)v0.x; o[1] = (_Float16)v0.y;
    o[2] = (_Float16)v0.z; o[3] = (_Float16)v0.w;
    o[4] = (_Float16)v1.x; o[5] = (_Float16)v1.y;
    o[6] = (_Float16)v1.z; o[7] = (_Float16)v1.w;
    *(f16x8*)(d + (size_t)i * 8) = o;
}

// ---------------- gather emb rows by token -> packed fragment A [4096][256] ----------------
__global__ __launch_bounds__(256) void gather_pack(
    const int* __restrict__ nodes, const float* __restrict__ emb,
    __hip_bfloat16* __restrict__ dst)
{
    int i = blockIdx.x * 256 + threadIdx.x;      // 131072 chunks
    int lane = i & 63, ks = (i >> 6) & 7, j = i >> 9;
    int g = lane >> 4, c = lane & 15;
    int row = j * 16 + c;
    int tok = nodes[row];
    const float* s = emb + (size_t)tok * HH + ks * 32 + g * 8;
    float4 v0 = *(const float4*)s;
    float4 v1 = *(const float4*)(s + 4);
    bf16x8 o;
    o[0] = (short)f2bf(v0.x); o[1] = (short)f2bf(v0.y);
    o[2] = (short)f2bf(v0.z); o[3] = (short)f2bf(v0.w);
    o[4] = (short)f2bf(v1.x); o[5] = (short)f2bf(v1.y);
    o[6] = (short)f2bf(v1.z); o[7] = (short)f2bf(v1.w);
    *(bf16x8*)(dst + (size_t)i * 8) = o;
}

// ---------------- transpose 256x256 f32 x3 (latent weights), slot = blockIdx.y ----------------
__global__ __launch_bounds__(256) void pack_lat3(
    const float* __restrict__ s0, const float* __restrict__ s1,
    const float* __restrict__ s2, float* __restrict__ dst)
{
    int i = blockIdx.x * 256 + threadIdx.x;   // 65536
    int slot = blockIdx.y;
    const float* src = (slot == 0) ? s0 : (slot == 1) ? s1 : s2;
    float* d = dst + (size_t)slot * 65536;
    int j = i & 255, k = i >> 8;
    d[(size_t)k * 256 + j] = src[(size_t)j * 256 + k];
}

// ============ register-stationary GEMM, packed operands ============
template<bool WRITE_C, bool HAS_BIAS, bool LSE_PARTIAL, bool LSE_SUB>
__global__ __launch_bounds__(256, 4) void gemm_rs(
    const __hip_bfloat16* __restrict__ A,
    const __hip_bfloat16* __restrict__ B,
    int ldc, int nchunks, int ntiles,
    const float* __restrict__ bias,
    const float* __restrict__ lse,
    float* __restrict__ C,
    float* __restrict__ pm, float* __restrict__ ps)
{
    __shared__ float lds_st[WRITE_C ? (4 * 16 * 68) : 1];

    const int tid  = threadIdx.x;
    const int w    = tid >> 6;
    const int lane = tid & 63;
    const int g    = lane >> 4;
    const int c    = lane & 15;
    const int m0   = blockIdx.x * 64;
    const int row16 = m0 + w * 16;
    const int n0   = blockIdx.y * (nchunks * 64);
    const int jb0  = n0 >> 4;

    bf16x8 a[8];
    {
        const __hip_bfloat16* ap = A + (((size_t)(row16 >> 4) * 8) * 64 + lane) * 8;
#pragma unroll
        for (int ks = 0; ks < 8; ++ks) a[ks] = *(const bf16x8*)(ap + ks * 512);
    }

    float mrun[4], srun[4];
#pragma unroll
    for (int r = 0; r < 4; ++r) { mrun[r] = -3.0e38f; srun[r] = 0.f; }

    float lsev[4];
    if (LSE_SUB) {
#pragma unroll
        for (int r = 0; r < 4; ++r) lsev[r] = lse[row16 + 4 * g + r];
    }

    for (int nc = 0; nc < nchunks; ++nc) {
        const int nb = n0 + nc * 64;
        const __hip_bfloat16* bp = B + (((size_t)(jb0 + nc * 4) * 8) * 64 + lane) * 8;

        f32x4 acc[4];
#pragma unroll
        for (int nf = 0; nf < 4; ++nf) acc[nf] = (f32x4){0.f, 0.f, 0.f, 0.f};

#pragma unroll
        for (int ks = 0; ks < 8; ++ks) {
            bf16x8 b0 = *(const bf16x8*)(bp + (0 * 8 + ks) * 512);
            bf16x8 b1 = *(const bf16x8*)(bp + (1 * 8 + ks) * 512);
            bf16x8 b2 = *(const bf16x8*)(bp + (2 * 8 + ks) * 512);
            bf16x8 b3 = *(const bf16x8*)(bp + (3 * 8 + ks) * 512);
            acc[0] = __builtin_amdgcn_mfma_f32_16x16x32_bf16(a[ks], b0, acc[0], 0, 0, 0);
            acc[1] = __builtin_amdgcn_mfma_f32_16x16x32_bf16(a[ks], b1, acc[1], 0, 0, 0);
            acc[2] = __builtin_amdgcn_mfma_f32_16x16x32_bf16(a[ks], b2, acc[2], 0, 0, 0);
            acc[3] = __builtin_amdgcn_mfma_f32_16x16x32_bf16(a[ks], b3, acc[3], 0, 0, 0);
        }

        float bv[4] = {0.f, 0.f, 0.f, 0.f};
        if (HAS_BIAS) {
#pragma unroll
            for (int nf = 0; nf < 4; ++nf) bv[nf] = bias[nb + nf * 16 + c];
        }

        if (LSE_PARTIAL) {
#pragma unroll
            for (int r = 0; r < 4; ++r) {
                float l0 = acc[0][r] + bv[0];
                float l1 = acc[1][r] + bv[1];
                float l2 = acc[2][r] + bv[2];
                float l3 = acc[3][r] + bv[3];
                float mc = fmaxf(fmaxf(l0, l1), fmaxf(l2, l3));
                float mn = fmaxf(mrun[r], mc);
                srun[r] = srun[r] * __expf(mrun[r] - mn)
                        + __expf(l0 - mn) + __expf(l1 - mn)
                        + __expf(l2 - mn) + __expf(l3 - mn);
                mrun[r] = mn;
            }
        }

        if (WRITE_C) {
            const int base = w * (16 * 68);
#pragma unroll
            for (int nf = 0; nf < 4; ++nf)
#pragma unroll
                for (int r = 0; r < 4; ++r) {
                    float v = acc[nf][r] + bv[nf];
                    if (LSE_SUB) v -= lsev[r];
                    lds_st[base + (4 * g + r) * 68 + nf * 16 + c] = v;
                }
#pragma unroll
            for (int i = 0; i < 4; ++i) {
                int lr = i * 4 + g;
                float4 v = *(const float4*)&lds_st[base + lr * 68 + c * 4];
                *(float4*)(C + (size_t)(row16 + lr) * ldc + nb + c * 4) = v;
            }
        }
    }

    if (LSE_PARTIAL) {
#pragma unroll
        for (int r = 0; r < 4; ++r) {
            float m = mrun[r], s = srun[r];
#pragma unroll
            for (int mk = 1; mk <= 8; mk <<= 1) {
                float m2 = __shfl_xor(m, mk);
                float s2 = __shfl_xor(s, mk);
                float mn = fmaxf(m, m2);
                s = s * __expf(m - mn) + s2 * __expf(m2 - mn);
                m = mn;
            }
            if (c == 0) {
                int row = row16 + 4 * g + r;
                pm[(size_t)row * ntiles + blockIdx.y] = m;
                ps[(size_t)row * ntiles + blockIdx.y] = s;
            }
        }
    }
}

// ============ fused recurrence v8: d-parallel, ZERO inter-block sync ============
// 8 blocks x 512 thr (8 waves). Block owns 16 INDEPENDENT d-rows (the scan is
// vmapped over d!) and computes their full 64-step chain + latent locally.
// h lives in block LDS (hpk A-frag f16 + hof f32). Wave = j8-slice (32 cols),
// computes BOTH variants for its cols (12 tiles); weights streamed from L2
// each step (768KB/block, perfectly coalesced 1KB/instr). Gate is in-register:
// each thread's acc holds both variants for its (d,j) -> compile-time-indexed
// ternary select. Decoder outs: one coalesced 16B/thread pass from hpk.
__global__ __launch_bounds__(512) void rnn_fused8(
    const unsigned char* __restrict__ ecan,
    const float* __restrict__ gi,          // [4096][3072]
    const _Float16* __restrict__ Wr,       // [4 slots][8 j8][6 tt][8 ks][64][8]
    const float* __restrict__ ecbih, const float* __restrict__ ecbhh,
    const float* __restrict__ esbih, const float* __restrict__ esbhh,
    const float* __restrict__ dcbih, const float* __restrict__ dcbhh,
    const float* __restrict__ dsbih, const float* __restrict__ dsbhh,
    const float* __restrict__ WmT, const float* __restrict__ WlT,
    const float* __restrict__ WhT,
    const float* __restrict__ b_mean, const float* __restrict__ b_logv,
    const float* __restrict__ b_l2h,
    const float* __restrict__ enc_init, const float* __restrict__ eps,
    float* __restrict__ out_mean, float* __restrict__ out_logv,
    float* __restrict__ out_z,
    __hip_bfloat16* __restrict__ outs_pk)
{
    __shared__ _Float16 hpk[512 * 8];           // 8KB: h in A-frag layout (16 rows)
    __shared__ float    hof[16 * HOFP];         // 16.5KB: h in f32
    __shared__ float    zl [16 * HOFP];         // 16.5KB: latent scratch
    __shared__ float    bsum[2][4][256];        // 8KB: per-variant br,bz,bin,bhn
    __shared__ unsigned char ecan_l[TT * DD];   // 4KB

    const int d0   = blockIdx.x * 16;
    const int tid  = threadIdx.x;
    const int j8   = tid >> 6;                  // wave = 32-col j-slice
    const int lane = tid & 63;
    const int g    = lane >> 4;
    const int c    = lane & 15;

    for (int u = tid; u < TT * DD; u += 512) ecan_l[u] = ecan[u];

    // ---- init h = enc_init (hpk + hof) ----
    {
        int u = tid;                            // 512 chunks
        int ks = u >> 6, ln = u & 63, lg = ln >> 4, lc = ln & 15;
        const float* s = enc_init + (size_t)(d0 + lc) * HH + ks * 32 + lg * 8;
        float4 v0 = *(const float4*)s;
        float4 v1 = *(const float4*)(s + 4);
        f16x8 o;
        o[0] = (_Float16)v0.x; o[1] = (_Float16)v0.y;
        o[2] = (_Float16)v0.z; o[3] = (_Float16)v0.w;
        o[4] = (_Float16)v1.x; o[5] = (_Float16)v1.y;
        o[6] = (_Float16)v1.z; o[7] = (_Float16)v1.w;
        *(f16x8*)&hpk[(size_t)u * 8] = o;
    }
    for (int u = tid; u < 16 * HH; u += 512)
        hof[(u >> 8) * HOFP + (u & 255)] = enc_init[(size_t)(d0 + (u >> 8)) * HH + (u & 255)];
    __syncthreads();

    for (int p = 0; p < 2; ++p) {
        // ---- biases into LDS (once per phase) ----
        {
            const float* bihc = p ? dcbih : ecbih;
            const float* bhhc = p ? dcbhh : ecbhh;
            const float* bihs = p ? dsbih : esbih;
            const float* bhhs = p ? dsbhh : esbhh;
            if (tid < 256) {
                bsum[0][0][tid] = bihc[tid]       + bhhc[tid];
                bsum[0][1][tid] = bihc[256 + tid] + bhhc[256 + tid];
                bsum[0][2][tid] = bihc[512 + tid];
                bsum[0][3][tid] = bhhc[512 + tid];
            } else {
                int t = tid - 256;
                bsum[1][0][t] = bihs[t]       + bhhs[t];
                bsum[1][1][t] = bihs[256 + t] + bhhs[256 + t];
                bsum[1][2][t] = bihs[512 + t];
                bsum[1][3][t] = bhhs[512 + t];
            }
        }
        __syncthreads();

        for (int st = 0; st < TT; ++st) {
            // ---- A-frags from hpk ----
            f16x8 af[8];
#pragma unroll
            for (int ks = 0; ks < 8; ++ks)
                af[ks] = *(const f16x8*)&hpk[((size_t)(ks * 64 + lane)) * 8];
            __syncthreads();    // all waves read af before any gate rewrites hpk

            // ---- MFMA: both variants x 6 tiles, weights streamed from L2 ----
            f32x4 acc[12];
#pragma unroll
            for (int q = 0; q < 12; ++q) acc[q] = (f32x4){0.f, 0.f, 0.f, 0.f};
#pragma unroll
            for (int vv = 0; vv < 2; ++vv)
#pragma unroll
                for (int tt = 0; tt < 6; ++tt) {
                    f32x4 a = (f32x4){0.f, 0.f, 0.f, 0.f};
#pragma unroll
                    for (int ks = 0; ks < 8; ++ks) {
                        const f16x8 bf = *(const f16x8*)(Wr
                            + (((size_t)(p * 2 + vv) * 384 + (j8 * 6 + tt) * 8 + ks) * 64 + lane) * 8);
                        a = __builtin_amdgcn_mfma_f32_16x16x32_f16(af[ks], bf, a, 0, 0, 0);
                    }
                    acc[vv * 6 + tt] = a;
                }

            // ---- gate fully in-register (compile-time acc indices) ----
#pragma unroll
            for (int rr = 0; rr < 4; ++rr) {
                const int drow = 4 * g + rr;
                const bool e = ecan_l[st * DD + d0 + drow] != 0;
                const int vb = e ? 0 : 1;
                const float* gp = gi + (size_t)(st * DD + d0 + drow) * 3072
                                + p * 1536 + vb * 768;
#pragma unroll
                for (int jg2 = 0; jg2 < 2; ++jg2) {
                    const int j = j8 * 32 + jg2 * 16 + c;
                    float gr_ = gp[j], gz_ = gp[256 + j], gn_ = gp[512 + j];
                    float ghr = e ? acc[jg2 * 3 + 0][rr] : acc[6 + jg2 * 3 + 0][rr];
                    float ghz = e ? acc[jg2 * 3 + 1][rr] : acc[6 + jg2 * 3 + 1][rr];
                    float ghn = e ? acc[jg2 * 3 + 2][rr] : acc[6 + jg2 * 3 + 2][rr];
                    float br  = bsum[vb][0][j];
                    float bz  = bsum[vb][1][j];
                    float bni = bsum[vb][2][j];
                    float bnh = bsum[vb][3][j];
                    float rg = 1.f / (1.f + __expf(-(gr_ + br + ghr)));
                    float zg = 1.f / (1.f + __expf(-(gz_ + bz + ghz)));
                    float nn = tanhf(gn_ + bni + rg * (ghn + bnh));
                    float hold = hof[drow * HOFP + j];
                    float hv = (1.f - zg) * nn + zg * hold;
                    hof[drow * HOFP + j] = hv;
                    hpk[((size_t)((j >> 5) * 64 + ((j >> 3) & 3) * 16 + drow)) * 8 + (j & 7)]
                        = (_Float16)hv;
                }
            }
            __syncthreads();    // gates done -> hpk consistent

            // ---- decoder: coalesced packed-outs write (1 chunk/thread) ----
            if (p) {
                int u = tid;
                f16x8 hv = *(const f16x8*)&hpk[(size_t)u * 8];
                bf16x8 ob;
#pragma unroll
                for (int m = 0; m < 8; ++m) ob[m] = (short)f2bf((float)hv[m]);
                size_t och = ((size_t)(st * 8 + blockIdx.x) * 8 + (u >> 6)) * 64 + (u & 63);
                *(bf16x8*)((unsigned short*)outs_pk + och * 8) = ob;
            }
        }

        if (p == 0) {
            // ---- latent head, all block-local (16 rows) ----
            const int d16 = tid >> 5, q5 = tid & 31;
            const int dg = d0 + d16;
            f32x4 mean0, mean1, logv0, logv1;
            {
                f32x4 sm0 = {0,0,0,0}, sm1 = {0,0,0,0}, sl0 = {0,0,0,0}, sl1 = {0,0,0,0};
                const float* hl = hof + d16 * HOFP;
                for (int k = 0; k < HH; ++k) {
                    float hv = hl[k];
                    const f32x4* wm = (const f32x4*)(WmT + (size_t)k * 256 + q5 * 8);
                    const f32x4* wl = (const f32x4*)(WlT + (size_t)k * 256 + q5 * 8);
                    sm0 += hv * wm[0]; sm1 += hv * wm[1];
                    sl0 += hv * wl[0]; sl1 += hv * wl[1];
                }
                mean0 = sm0 + *(const f32x4*)(b_mean + q5 * 8);
                mean1 = sm1 + *(const f32x4*)(b_mean + q5 * 8 + 4);
                logv0 = sl0 + *(const f32x4*)(b_logv + q5 * 8);
                logv1 = sl1 + *(const f32x4*)(b_logv + q5 * 8 + 4);
                *(f32x4*)(out_mean + (size_t)dg * ZZ + q5 * 8)     = mean0;
                *(f32x4*)(out_mean + (size_t)dg * ZZ + q5 * 8 + 4) = mean1;
                *(f32x4*)(out_logv + (size_t)dg * ZZ + q5 * 8)     = logv0;
                *(f32x4*)(out_logv + (size_t)dg * ZZ + q5 * 8 + 4) = logv1;
            }
            {
                f32x4 ep0 = *(const f32x4*)(eps + (size_t)dg * ZZ + q5 * 8);
                f32x4 ep1 = *(const f32x4*)(eps + (size_t)dg * ZZ + q5 * 8 + 4);
                f32x4 zv0, zv1;
#pragma unroll
                for (int m = 0; m < 4; ++m) {
                    zv0[m] = ep0[m] * __expf(0.5f * logv0[m]) + mean0[m];
                    zv1[m] = ep1[m] * __expf(0.5f * logv1[m]) + mean1[m];
                }
                *(f32x4*)(out_z + (size_t)dg * ZZ + q5 * 8)     = zv0;
                *(f32x4*)(out_z + (size_t)dg * ZZ + q5 * 8 + 4) = zv1;
                *(f32x4*)(zl + d16 * HOFP + q5 * 8)     = zv0;
                *(f32x4*)(zl + d16 * HOFP + q5 * 8 + 4) = zv1;
            }
            __syncthreads();    // zl complete
            {
                f32x4 s0 = {0,0,0,0}, s1 = {0,0,0,0};
                const float* zp = zl + d16 * HOFP;
                for (int k = 0; k < ZZ; ++k) {
                    float zv = zp[k];
                    const f32x4* wh = (const f32x4*)(WhT + (size_t)k * 256 + q5 * 8);
                    s0 += zv * wh[0]; s1 += zv * wh[1];
                }
                f32x4 h0a = s0 + *(const f32x4*)(b_l2h + q5 * 8);
                f32x4 h0b = s1 + *(const f32x4*)(b_l2h + q5 * 8 + 4);
                *(f32x4*)(hof + d16 * HOFP + q5 * 8)     = h0a;
                *(f32x4*)(hof + d16 * HOFP + q5 * 8 + 4) = h0b;
                // hpk: j = q5*8 spans exactly one 8-elem chunk
                f16x8 pk;
#pragma unroll
                for (int m = 0; m < 4; ++m) { pk[m] = (_Float16)h0a[m]; pk[4 + m] = (_Float16)h0b[m]; }
                int chunk = (q5 >> 2) * 64 + (q5 & 3) * 16 + d16;
                *(f16x8*)&hpk[(size_t)chunk * 8] = pk;
            }
            __syncthreads();
        }
    }
}

// ---------------- per-row logsumexp merge (one wave per row, nt <= 64) ----------------
__global__ __launch_bounds__(64) void lse_reduce(
    const float* __restrict__ pm, const float* __restrict__ ps,
    float* __restrict__ lse, int nt)
{
    int row = blockIdx.x;
    int l = threadIdx.x;
    float m = (l < nt) ? pm[(size_t)row * nt + l] : -3.0e38f;
    float s = (l < nt) ? ps[(size_t)row * nt + l] : 0.f;
    for (int mk = 1; mk <= 32; mk <<= 1) {
        float m2 = __shfl_xor(m, mk);
        float s2 = __shfl_xor(s, mk);
        float mn = fmaxf(m, m2);
        s = s * __expf(m - mn) + s2 * __expf(m2 - mn);
        m = mn;
    }
    if (l == 0) lse[row] = m + logf(s);
}

extern "C" void kernel_launch(void* const* d_in, const int* in_sizes, int n_in,
                              void* d_out, int out_size, void* d_ws, size_t ws_size,
                              hipStream_t stream)
{
    const int*           nodes     = (const int*)d_in[0];
    const unsigned char* edges_raw = (const unsigned char*)d_in[1];
    const float* emb    = (const float*)d_in[2];
    const float* ecWih  = (const float*)d_in[3];
    const float* ecWhh  = (const float*)d_in[4];
    const float* ecbih  = (const float*)d_in[5];
    const float* ecbhh  = (const float*)d_in[6];
    const float* esWih  = (const float*)d_in[7];
    const float* esWhh  = (const float*)d_in[8];
    const float* esbih  = (const float*)d_in[9];
    const float* esbhh  = (const float*)d_in[10];
    const float* dcWih  = (const float*)d_in[11];
    const float* dcWhh  = (const float*)d_in[12];
    const float* dcbih  = (const float*)d_in[13];
    const float* dcbhh  = (const float*)d_in[14];
    const float* dsWih  = (const float*)d_in[15];
    const float* dsWhh  = (const float*)d_in[16];
    const float* dsbih  = (const float*)d_in[17];
    const float* dsbhh  = (const float*)d_in[18];
    const float* W_mean = (const float*)d_in[19];
    const float* b_mean = (const float*)d_in[20];
    const float* W_logv = (const float*)d_in[21];
    const float* b_logv = (const float*)d_in[22];
    const float* W_l2h  = (const float*)d_in[23];
    const float* b_l2h  = (const float*)d_in[24];
    const float* W_out  = (const float*)d_in[25];
    const float* b_out  = (const float*)d_in[26];
    const float* enc_init = (const float*)d_in[27];
    const float* eps    = (const float*)d_in[28];

    float* out      = (float*)d_out;
    float* out_mean = out + (size_t)TT * DD * VV;
    float* out_logv = out_mean + DD * ZZ;
    float* out_z    = out_logv + DD * ZZ;
    float* gi       = out;                  // scratch in logits region: [4096][3072]

    char* ws = (char*)d_ws;
    __hip_bfloat16* outs_pk = (__hip_bfloat16*)(ws + 0);         // 2MB
    __hip_bfloat16* Ap      = (__hip_bfloat16*)(ws + 2097152);   // 2MB
    __hip_bfloat16* Wp      = (__hip_bfloat16*)(ws + 4194304);   // 16.4MB
    __hip_bfloat16* Bp_all  = (__hip_bfloat16*)(ws + 20971520);  // 1.5MB
    _Float16*       Wr      = (_Float16*)(ws + 22544384);        // 1.5MB rnn-frag Whh x4
    float*          WmT     = (float*)(ws + 24117248);           // 256KB (x3 contiguous)
    float*          pm      = (float*)(ws + 24903680);           // 800KB
    float*          ps      = (float*)(ws + 25722880);           // 800KB
    float*          lse     = (float*)(ws + 26542080);           // 16KB
    unsigned char*  ecan    = (unsigned char*)(ws + 26558464);   // 4KB
    float*          WlT     = WmT + 65536;
    float*          WhT     = WmT + 131072;

    edge_canon_k<<<1, 256, 0, stream>>>(edges_raw, ecan);
    pack_frag<<<4000, 256, 0, stream>>>(W_out, Wp, 2000 * 8 * 64);
    pack_frag4<<<dim3(96, 4), 256, 0, stream>>>(ecWih, esWih, dcWih, dsWih, Bp_all);
    pack_wrnn4<<<dim3(96, 4), 256, 0, stream>>>(ecWhh, esWhh, dcWhh, dsWhh, Wr);
    pack_lat3<<<dim3(256, 3), 256, 0, stream>>>(W_mean, W_logv, W_l2h, WmT);
    gather_pack<<<512, 256, 0, stream>>>(nodes, emb, Ap);

    // gi[4096][3072] = emb-gather x [all 4 W_ih]^T  (into d_out scratch)
    gemm_rs<true, false, false, false><<<dim3(64, 6), 256, 0, stream>>>(
        Ap, Bp_all, 3072, 8, 6, nullptr, nullptr, gi, nullptr, nullptr);

    // fused recurrence: encoder -> latent -> h0 -> decoder, d-parallel, no sync
    rnn_fused8<<<8, 512, 0, stream>>>(
        ecan, gi, Wr,
        ecbih, ecbhh, esbih, esbhh, dcbih, dcbhh, dsbih, dsbhh,
        WmT, WlT, WhT, b_mean, b_logv, b_l2h,
        enc_init, eps, out_mean, out_logv, out_z, outs_pk);

    // pass A: LSE partials only (no C write)
    gemm_rs<false, true, true, false><<<dim3(64, NTL), 256, 0, stream>>>(
        outs_pk, Wp, VV, 10, NTL, b_out, nullptr, nullptr, pm, ps);
    lse_reduce<<<4096, 64, 0, stream>>>(pm, ps, lse, NTL);
    // pass B: recompute, write logp = logits - lse
    gemm_rs<true, true, false, true><<<dim3(64, NTL), 256, 0, stream>>>(
        outs_pk, Wp, VV, 10, NTL, b_out, lse, out, nullptr, nullptr);
}

// Round 14
// 902.710 us; speedup vs baseline: 1.9410x; 1.9410x over previous
//
#include <hip/hip_runtime.h>
#include <hip/hip_bf16.h>

#define TT 32
#define DD 128
#define HH 256
#define VV 32000
#define ZZ 256
#define NTL 50            // n-slabs for V-GEMM (50 x 640 = 32000)
#define NBLK 16           // rnn blocks (8 j-slices x 2 variants)
#define GHLP 100          // ghl row pitch in f16 (96 + 4 pad)

typedef __attribute__((ext_vector_type(8))) short bf16x8;
typedef __attribute__((ext_vector_type(4))) float f32x4;
typedef __attribute__((ext_vector_type(8))) _Float16 f16x8;

static __device__ inline unsigned short f2bf(float x) {
    __hip_bfloat16 h = __float2bfloat16(x);
    return *(unsigned short*)&h;
}

static __device__ inline unsigned long long pack4h(_Float16 a, _Float16 b,
                                                   _Float16 c, _Float16 d) {
    union { _Float16 h[4]; unsigned long long u; } x;
    x.h[0] = a; x.h[1] = b; x.h[2] = c; x.h[3] = d;
    return x.u;
}

// ---------------- edges canonicalizer (bool-vs-int32 layout detect) ----------------
__global__ void edge_canon_k(const unsigned char* __restrict__ eb,
                             unsigned char* __restrict__ canon)
{
    __shared__ int flag;
    if (threadIdx.x == 0) flag = 0;
    __syncthreads();
    int acc = 0;
    for (int i = threadIdx.x; i < TT * DD; i += 256)
        if (i & 3) acc |= eb[i];
    if (acc) atomicOr(&flag, 1);
    __syncthreads();
    const bool is_i32 = (flag == 0);
    for (int i = threadIdx.x; i < TT * DD; i += 256)
        canon[i] = is_i32 ? eb[4 * (size_t)i] : eb[i];
}

// ---------------- pack f32 [nrow16*16][256] -> fragment-linear bf16 (W_out) ----------------
__global__ __launch_bounds__(256) void pack_frag(
    const float* __restrict__ src, __hip_bfloat16* __restrict__ dst, int nchunks_total)
{
    int i = blockIdx.x * 256 + threadIdx.x;
    if (i >= nchunks_total) return;
    int lane = i & 63, ks = (i >> 6) & 7, j = i >> 9;
    int g = lane >> 4, c = lane & 15;
    const float* s = src + (size_t)(j * 16 + c) * HH + ks * 32 + g * 8;
    float4 v0 = *(const float4*)s;
    float4 v1 = *(const float4*)(s + 4);
    bf16x8 o;
    o[0] = (short)f2bf(v0.x); o[1] = (short)f2bf(v0.y);
    o[2] = (short)f2bf(v0.z); o[3] = (short)f2bf(v0.w);
    o[4] = (short)f2bf(v1.x); o[5] = (short)f2bf(v1.y);
    o[6] = (short)f2bf(v1.z); o[7] = (short)f2bf(v1.w);
    *(bf16x8*)(dst + (size_t)i * 8) = o;
}

// ---------------- pack 4 Wih matrices -> fragment-linear bf16, slot = blockIdx.y ----------------
__global__ __launch_bounds__(256) void pack_frag4(
    const float* __restrict__ s0, const float* __restrict__ s1,
    const float* __restrict__ s2, const float* __restrict__ s3,
    __hip_bfloat16* __restrict__ dst)
{
    int i = blockIdx.x * 256 + threadIdx.x;
    if (i >= 24576) return;
    int slot = blockIdx.y;
    const float* src = (slot == 0) ? s0 : (slot == 1) ? s1 : (slot == 2) ? s2 : s3;
    __hip_bfloat16* d = dst + (size_t)slot * 196608;
    int lane = i & 63, ks = (i >> 6) & 7, j = i >> 9;
    int g = lane >> 4, c = lane & 15;
    const float* s = src + (size_t)(j * 16 + c) * HH + ks * 32 + g * 8;
    float4 v0 = *(const float4*)s;
    float4 v1 = *(const float4*)(s + 4);
    bf16x8 o;
    o[0] = (short)f2bf(v0.x); o[1] = (short)f2bf(v0.y);
    o[2] = (short)f2bf(v0.z); o[3] = (short)f2bf(v0.w);
    o[4] = (short)f2bf(v1.x); o[5] = (short)f2bf(v1.y);
    o[6] = (short)f2bf(v1.z); o[7] = (short)f2bf(v1.w);
    *(bf16x8*)(d + (size_t)i * 8) = o;
}

// ---------------- pack 4 Whh matrices -> rnn B-frag f16, slot = blockIdx.y ----------------
// chunk = ((j8*6 + tt)*8 + ks), lane=(g,c): holds W[gt*256 + j8*32 + jg2*16 + c][ks*32+g*8..+8]
// where tt = jg2*3 + gt.
__global__ __launch_bounds__(256) void pack_wrnn4(
    const float* __restrict__ s0, const float* __restrict__ s1,
    const float* __restrict__ s2, const float* __restrict__ s3,
    _Float16* __restrict__ dst)
{
    int i = blockIdx.x * 256 + threadIdx.x;
    if (i >= 24576) return;
    int slot = blockIdx.y;
    const float* src = (slot == 0) ? s0 : (slot == 1) ? s1 : (slot == 2) ? s2 : s3;
    _Float16* d = dst + (size_t)slot * 196608;
    int lane = i & 63;
    int t2 = i >> 6;
    int ks = t2 & 7;
    int t3 = t2 >> 3;
    int tt = t3 % 6;
    int j8 = t3 / 6;
    int g = lane >> 4, c = lane & 15;
    int jg2 = tt / 3, gt = tt % 3;
    int srow = gt * 256 + j8 * 32 + jg2 * 16 + c;
    int scol = ks * 32 + g * 8;
    const float* s = src + (size_t)srow * HH + scol;
    float4 v0 = *(const float4*)s;
    float4 v1 = *(const float4*)(s + 4);
    f16x8 o;
    o[0] = (_Float16)v0.x; o[1] = (_Float16)v0.y;
    o[2] = (_Float16)v0.z; o[3] = (_Float16)v0.w;
    o[4] = (_Float16)v1.x; o[5] = (_Float16)v1.y;
    o[6] = (_Float16)v1.z; o[7] = (_Float16)v1.w;
    *(f16x8*)(d + (size_t)i * 8) = o;
}

// ---------------- gather emb rows by token -> packed fragment A [4096][256] ----------------
__global__ __launch_bounds__(256) void gather_pack(
    const int* __restrict__ nodes, const float* __restrict__ emb,
    __hip_bfloat16* __restrict__ dst)
{
    int i = blockIdx.x * 256 + threadIdx.x;      // 131072 chunks
    int lane = i & 63, ks = (i >> 6) & 7, j = i >> 9;
    int g = lane >> 4, c = lane & 15;
    int row = j * 16 + c;
    int tok = nodes[row];
    const float* s = emb + (size_t)tok * HH + ks * 32 + g * 8;
    float4 v0 = *(const float4*)s;
    float4 v1 = *(const float4*)(s + 4);
    bf16x8 o;
    o[0] = (short)f2bf(v0.x); o[1] = (short)f2bf(v0.y);
    o[2] = (short)f2bf(v0.z); o[3] = (short)f2bf(v0.w);
    o[4] = (short)f2bf(v1.x); o[5] = (short)f2bf(v1.y);
    o[6] = (short)f2bf(v1.z); o[7] = (short)f2bf(v1.w);
    *(bf16x8*)(dst + (size_t)i * 8) = o;
}

// ---------------- transpose 256x256 f32 x3 (latent weights), slot = blockIdx.y ----------------
__global__ __launch_bounds__(256) void pack_lat3(
    const float* __restrict__ s0, const float* __restrict__ s1,
    const float* __restrict__ s2, float* __restrict__ dst)
{
    int i = blockIdx.x * 256 + threadIdx.x;   // 65536
    int slot = blockIdx.y;
    const float* src = (slot == 0) ? s0 : (slot == 1) ? s1 : s2;
    float* d = dst + (size_t)slot * 65536;
    int j = i & 255, k = i >> 8;
    d[(size_t)k * 256 + j] = src[(size_t)j * 256 + k];
}

// ============ register-stationary GEMM, packed operands, M-doubled ============
// MT m-tiles per wave share each B-fragment load (MFMA:load ratio x MT).
template<int MT, bool WRITE_C, bool HAS_BIAS, bool LSE_PARTIAL, bool LSE_SUB>
__global__ __launch_bounds__(256, 2) void gemm_rs(
    const __hip_bfloat16* __restrict__ A,
    const __hip_bfloat16* __restrict__ B,
    int ldc, int nchunks, int ntiles,
    const float* __restrict__ bias,
    const float* __restrict__ lse,
    float* __restrict__ C,
    float* __restrict__ pm, float* __restrict__ ps)
{
    __shared__ float lds_st[WRITE_C ? (4 * 16 * 68) : 1];

    const int tid  = threadIdx.x;
    const int w    = tid >> 6;
    const int lane = tid & 63;
    const int g    = lane >> 4;
    const int c    = lane & 15;
    const int m0   = blockIdx.x * (64 * MT);
    const int n0   = blockIdx.y * (nchunks * 64);
    const int jb0  = n0 >> 4;

    bf16x8 a[MT][8];
#pragma unroll
    for (int mt = 0; mt < MT; ++mt) {
        const int row16 = m0 + mt * 64 + w * 16;
        const __hip_bfloat16* ap = A + (((size_t)(row16 >> 4) * 8) * 64 + lane) * 8;
#pragma unroll
        for (int ks = 0; ks < 8; ++ks) a[mt][ks] = *(const bf16x8*)(ap + ks * 512);
    }

    float mrun[MT][4], srun[MT][4];
#pragma unroll
    for (int mt = 0; mt < MT; ++mt)
#pragma unroll
        for (int r = 0; r < 4; ++r) { mrun[mt][r] = -3.0e38f; srun[mt][r] = 0.f; }

    float lsev[MT][4];
    if (LSE_SUB) {
#pragma unroll
        for (int mt = 0; mt < MT; ++mt)
#pragma unroll
            for (int r = 0; r < 4; ++r)
                lsev[mt][r] = lse[m0 + mt * 64 + w * 16 + 4 * g + r];
    }

    for (int nc = 0; nc < nchunks; ++nc) {
        const int nb = n0 + nc * 64;
        const __hip_bfloat16* bp = B + (((size_t)(jb0 + nc * 4) * 8) * 64 + lane) * 8;

        f32x4 acc[MT][4];
#pragma unroll
        for (int mt = 0; mt < MT; ++mt)
#pragma unroll
            for (int nf = 0; nf < 4; ++nf) acc[mt][nf] = (f32x4){0.f, 0.f, 0.f, 0.f};

#pragma unroll
        for (int ks = 0; ks < 8; ++ks) {
            bf16x8 b0 = *(const bf16x8*)(bp + (0 * 8 + ks) * 512);
            bf16x8 b1 = *(const bf16x8*)(bp + (1 * 8 + ks) * 512);
            bf16x8 b2 = *(const bf16x8*)(bp + (2 * 8 + ks) * 512);
            bf16x8 b3 = *(const bf16x8*)(bp + (3 * 8 + ks) * 512);
#pragma unroll
            for (int mt = 0; mt < MT; ++mt) {
                acc[mt][0] = __builtin_amdgcn_mfma_f32_16x16x32_bf16(a[mt][ks], b0, acc[mt][0], 0, 0, 0);
                acc[mt][1] = __builtin_amdgcn_mfma_f32_16x16x32_bf16(a[mt][ks], b1, acc[mt][1], 0, 0, 0);
                acc[mt][2] = __builtin_amdgcn_mfma_f32_16x16x32_bf16(a[mt][ks], b2, acc[mt][2], 0, 0, 0);
                acc[mt][3] = __builtin_amdgcn_mfma_f32_16x16x32_bf16(a[mt][ks], b3, acc[mt][3], 0, 0, 0);
            }
        }

        float bv[4] = {0.f, 0.f, 0.f, 0.f};
        if (HAS_BIAS) {
#pragma unroll
            for (int nf = 0; nf < 4; ++nf) bv[nf] = bias[nb + nf * 16 + c];
        }

        if (LSE_PARTIAL) {
#pragma unroll
            for (int mt = 0; mt < MT; ++mt)
#pragma unroll
                for (int r = 0; r < 4; ++r) {
                    float l0 = acc[mt][0][r] + bv[0];
                    float l1 = acc[mt][1][r] + bv[1];
                    float l2 = acc[mt][2][r] + bv[2];
                    float l3 = acc[mt][3][r] + bv[3];
                    float mc = fmaxf(fmaxf(l0, l1), fmaxf(l2, l3));
                    float mn = fmaxf(mrun[mt][r], mc);
                    srun[mt][r] = srun[mt][r] * __expf(mrun[mt][r] - mn)
                            + __expf(l0 - mn) + __expf(l1 - mn)
                            + __expf(l2 - mn) + __expf(l3 - mn);
                    mrun[mt][r] = mn;
                }
        }

        if (WRITE_C) {
            const int base = w * (16 * 68);
#pragma unroll
            for (int mt = 0; mt < MT; ++mt) {
                const int row16 = m0 + mt * 64 + w * 16;
#pragma unroll
                for (int nf = 0; nf < 4; ++nf)
#pragma unroll
                    for (int r = 0; r < 4; ++r) {
                        float v = acc[mt][nf][r] + bv[nf];
                        if (LSE_SUB) v -= lsev[mt][r];
                        lds_st[base + (4 * g + r) * 68 + nf * 16 + c] = v;
                    }
#pragma unroll
                for (int i = 0; i < 4; ++i) {
                    int lr = i * 4 + g;
                    float4 v = *(const float4*)&lds_st[base + lr * 68 + c * 4];
                    *(float4*)(C + (size_t)(row16 + lr) * ldc + nb + c * 4) = v;
                }
            }
        }
    }

    if (LSE_PARTIAL) {
#pragma unroll
        for (int mt = 0; mt < MT; ++mt)
#pragma unroll
            for (int r = 0; r < 4; ++r) {
                float m = mrun[mt][r], s = srun[mt][r];
#pragma unroll
                for (int mk = 1; mk <= 8; mk <<= 1) {
                    float m2 = __shfl_xor(m, mk);
                    float s2 = __shfl_xor(s, mk);
                    float mn = fmaxf(m, m2);
                    s = s * __expf(m - mn) + s2 * __expf(m2 - mn);
                    m = mn;
                }
                if (c == 0) {
                    int row = m0 + mt * 64 + w * 16 + 4 * g + r;
                    pm[(size_t)row * ntiles + blockIdx.y] = m;
                    ps[(size_t)row * ntiles + blockIdx.y] = s;
                }
            }
    }
}

// ============ fused recurrence v6 (proven): batched staging, 8B exchange, flag barrier ============
__global__ __launch_bounds__(512) void rnn_fused6(
    const unsigned char* __restrict__ ecan,
    const float* __restrict__ gi,          // [4096][3072]
    const _Float16* __restrict__ Wr,       // [4 slots][8 j8][6 tt][8 ks][64][8]
    const float* __restrict__ ecbih, const float* __restrict__ ecbhh,
    const float* __restrict__ esbih, const float* __restrict__ esbhh,
    const float* __restrict__ dcbih, const float* __restrict__ dcbhh,
    const float* __restrict__ dsbih, const float* __restrict__ dsbhh,
    const float* __restrict__ WmT, const float* __restrict__ WlT,
    const float* __restrict__ WhT,
    const float* __restrict__ b_mean, const float* __restrict__ b_logv,
    const float* __restrict__ b_l2h,
    const float* __restrict__ enc_init, const float* __restrict__ eps,
    float* __restrict__ out_mean, float* __restrict__ out_logv,
    float* __restrict__ out_z,
    __hip_bfloat16* __restrict__ outs_pk,
    _Float16* __restrict__ xh,             // [65][128][256] f16, write-once slots
    int* __restrict__ flags)               // [16]
{
    __shared__ _Float16 wlds[6 * 8 * 64 * 8];   // 48K
    __shared__ _Float16 hpk[64 * 64 * 8];       // 64K, A-frag layout of h
    __shared__ _Float16 ghl[DD * GHLP];         // 25K: gh tile [128][96+pad]
    __shared__ float    bsum[4 * 256];          // 4K: br,bz,bin,bhn
    __shared__ unsigned char ecan_l[TT * DD];   // 4K

    const int v   = blockIdx.x & 1;             // 0: child (e!=0), 1: sibling
    const int j8  = blockIdx.x >> 1;
    const int tid = threadIdx.x;
    const int w    = tid >> 6;
    const int lane = tid & 63;
    const int g    = lane >> 4;
    const int c    = lane & 15;
    const int dq   = w & 3;
    const int jg2  = w >> 2;

    for (int u = tid; u < TT * DD; u += 512) ecan_l[u] = ecan[u];

    // ---- init hpk from enc_init ----
    for (int u = tid; u < 4096; u += 512) {
        int chunk = u >> 6, ln = u & 63;
        int dt = chunk >> 3, ks = chunk & 7, lg = ln >> 4, lc = ln & 15;
        const float* s = enc_init + (size_t)(dt * 16 + lc) * HH + ks * 32 + lg * 8;
        float4 v0 = *(const float4*)s;
        float4 v1 = *(const float4*)(s + 4);
        f16x8 o;
        o[0] = (_Float16)v0.x; o[1] = (_Float16)v0.y;
        o[2] = (_Float16)v0.z; o[3] = (_Float16)v0.w;
        o[4] = (_Float16)v1.x; o[5] = (_Float16)v1.y;
        o[6] = (_Float16)v1.z; o[7] = (_Float16)v1.w;
        *(f16x8*)&hpk[(size_t)u * 8] = o;
    }
    __syncthreads();

    int bi = 0;   // barrier index == xh slot

    for (int p = 0; p < 2; ++p) {
        // ---- weights + biases into LDS, once per phase ----
        {
            const _Float16* wsrc = Wr + ((size_t)(p * 2 + v) * 8 + j8) * (3072 * 8);
            for (int idx = tid; idx < 3072; idx += 512)
                *(f16x8*)&wlds[(size_t)idx * 8] = *(const f16x8*)(wsrc + (size_t)idx * 8);
        }
        {
            const float* bih = p ? (v ? dsbih : dcbih) : (v ? esbih : ecbih);
            const float* bhh = p ? (v ? dsbhh : dcbhh) : (v ? esbhh : ecbhh);
            if (tid < 256) {
                bsum[tid]       = bih[tid]       + bhh[tid];
                bsum[256 + tid] = bih[256 + tid] + bhh[256 + tid];
                bsum[512 + tid] = bih[512 + tid];
                bsum[768 + tid] = bhh[512 + tid];
            }
        }
        __syncthreads();

        for (int st = 0; st < TT; ++st) {
            // ---- gi prefetch for this step's gate units ----
            f32x4 gpr0[3], gpr1[3];
            bool sel0, sel1;
            {
                const int u0 = tid, u1 = tid + 512;
                const int d0 = u0 >> 3, d1 = u1 >> 3;
                const int jgA = j8 * 32 + (u0 & 7) * 4;
                const int jgB = j8 * 32 + (u1 & 7) * 4;
                sel0 = (ecan_l[st * DD + d0] != 0) == (v == 0);
                sel1 = (ecan_l[st * DD + d1] != 0) == (v == 0);
                if (sel0) {
                    const float* gp = gi + (size_t)(st * DD + d0) * 3072 + p * 1536 + v * 768 + jgA;
                    gpr0[0] = *(const f32x4*)gp;
                    gpr0[1] = *(const f32x4*)(gp + 256);
                    gpr0[2] = *(const f32x4*)(gp + 512);
                }
                if (sel1) {
                    const float* gp = gi + (size_t)(st * DD + d1) * 3072 + p * 1536 + v * 768 + jgB;
                    gpr1[0] = *(const f32x4*)gp;
                    gpr1[1] = *(const f32x4*)(gp + 256);
                    gpr1[2] = *(const f32x4*)(gp + 512);
                }
            }

            // ---- MFMA: acc[dti][gate] from LDS h x LDS W ----
            f32x4 acc[2][3];
#pragma unroll
            for (int a = 0; a < 2; ++a)
#pragma unroll
                for (int b = 0; b < 3; ++b) acc[a][b] = (f32x4){0.f, 0.f, 0.f, 0.f};
#pragma unroll
            for (int ks = 0; ks < 8; ++ks) {
                f16x8 a0 = *(const f16x8*)&hpk[(((dq * 2 + 0) * 8 + ks) * 64 + lane) * 8];
                f16x8 a1 = *(const f16x8*)&hpk[(((dq * 2 + 1) * 8 + ks) * 64 + lane) * 8];
#pragma unroll
                for (int gt = 0; gt < 3; ++gt) {
                    f16x8 bf = *(const f16x8*)&wlds[(((jg2 * 3 + gt) * 8 + ks) * 64 + lane) * 8];
                    acc[0][gt] = __builtin_amdgcn_mfma_f32_16x16x32_f16(a0, bf, acc[0][gt], 0, 0, 0);
                    acc[1][gt] = __builtin_amdgcn_mfma_f32_16x16x32_f16(a1, bf, acc[1][gt], 0, 0, 0);
                }
            }

            // ---- acc -> ghl (f16) ----
#pragma unroll
            for (int dti = 0; dti < 2; ++dti) {
                const int dt = dq * 2 + dti;
#pragma unroll
                for (int gt = 0; gt < 3; ++gt)
#pragma unroll
                    for (int rr = 0; rr < 4; ++rr)
                        ghl[(dt * 16 + 4 * g + rr) * GHLP + gt * 32 + jg2 * 16 + c] =
                            (_Float16)acc[dti][gt][rr];
            }
            __syncthreads();

            // ---- gate: 2 units/thread, unit = (d, 4 consecutive j) ----
            _Float16* xcur = xh + (size_t)bi * (DD * HH);
#pragma unroll
            for (int uu = 0; uu < 2; ++uu) {
                const bool sel = uu ? sel1 : sel0;
                if (!sel) continue;
                const int u = tid + uu * 512;
                const int d = u >> 3, jq = u & 7;
                const int jl = jq * 4;
                const int jg_ = j8 * 32 + jl;
                const f32x4* gpr = uu ? gpr1 : gpr0;

                f32x4 br  = *(const f32x4*)&bsum[jg_];
                f32x4 bz  = *(const f32x4*)&bsum[256 + jg_];
                f32x4 bni = *(const f32x4*)&bsum[512 + jg_];
                f32x4 bnh = *(const f32x4*)&bsum[768 + jg_];
                const _Float16* gd = &ghl[d * GHLP];
                const int dt = d >> 4, lc = d & 15, ks = jg_ >> 5, lg = (jg_ >> 3) & 3;
                const int ch = ((dt * 8 + ks) * 64 + lg * 16 + lc);
                const _Float16* hop = &hpk[(size_t)ch * 8 + (jg_ & 7)];

                _Float16 hn[4];
                unsigned short ob[4];
#pragma unroll
                for (int m = 0; m < 4; ++m) {
                    float ghr = (float)gd[jl + m];
                    float ghz = (float)gd[32 + jl + m];
                    float ghn = (float)gd[64 + jl + m];
                    float rg = 1.f / (1.f + __expf(-(gpr[0][m] + br[m] + ghr)));
                    float zg = 1.f / (1.f + __expf(-(gpr[1][m] + bz[m] + ghz)));
                    float nn = tanhf(gpr[2][m] + bni[m] + rg * (ghn + bnh[m]));
                    float hv = (1.f - zg) * nn + zg * (float)hop[m];
                    hn[m] = (_Float16)hv;
                    ob[m] = f2bf(hv);
                }
                __hip_atomic_store((unsigned long long*)(xcur + (size_t)d * HH + jg_),
                                   pack4h(hn[0], hn[1], hn[2], hn[3]),
                                   __ATOMIC_RELAXED, __HIP_MEMORY_SCOPE_AGENT);
                if (p) {
                    union { unsigned short s[4]; unsigned long long u; } ou;
                    ou.s[0] = ob[0]; ou.s[1] = ob[1]; ou.s[2] = ob[2]; ou.s[3] = ob[3];
                    size_t och = ((size_t)(st * 8 + dt) * 8 + ks) * 64 + lg * 16 + lc;
                    *(unsigned long long*)((unsigned short*)outs_pk + och * 8 + (jg_ & 7)) = ou.u;
                }
            }
            __syncthreads();   // drains all waves' stores

            // ---- flag barrier ----
            if (tid == 0)
                __hip_atomic_store(&flags[blockIdx.x], bi + 1,
                                   __ATOMIC_RELAXED, __HIP_MEMORY_SCOPE_AGENT);
            if (tid < 64) {
                for (;;) {
                    int f = (tid < NBLK)
                          ? __hip_atomic_load(&flags[tid], __ATOMIC_RELAXED, __HIP_MEMORY_SCOPE_AGENT)
                          : 0x7fffffff;
                    if (__all(f >= bi + 1)) break;
                    __builtin_amdgcn_s_sleep(1);
                }
            }
            __syncthreads();

            // ---- staging: batched 8x16B loads -> hpk ----
            {
                const _Float16* xr = xh + (size_t)bi * (DD * HH);
                f16x8 tv[8];
#pragma unroll
                for (int i = 0; i < 8; ++i) {
                    int u = tid + i * 512;
                    int chunk = u >> 6, ln = u & 63;
                    int dt = chunk >> 3, ks = chunk & 7, lg = ln >> 4, lc = ln & 15;
                    tv[i] = *(const f16x8*)(xr + (size_t)(dt * 16 + lc) * HH + ks * 32 + lg * 8);
                }
#pragma unroll
                for (int i = 0; i < 8; ++i)
                    *(f16x8*)&hpk[(size_t)(tid + i * 512) * 8] = tv[i];
            }
            __syncthreads();
            ++bi;
        }

        if (p == 0) {
            // ---- latent head, d-sharded (8 rows per block) ----
            float* hlin = (float*)ghl;          // reuse ghl (needs 8KB)
            const int d8 = tid >> 6;
            const int q  = tid & 63;
            const int dg = blockIdx.x * 8 + d8;
            for (int u = tid; u < 2048; u += 512) {
                int du = u >> 8, k = u & 255;
                int d = blockIdx.x * 8 + du;
                hlin[du * 256 + k] = (float)hpk[(((size_t)(d >> 4) * 8 + (k >> 5)) * 64
                                      + ((k >> 3) & 3) * 16 + (d & 15)) * 8 + (k & 7)];
            }
            __syncthreads();
            f32x4 mean4, logv4;
            {
                f32x4 sm = {0, 0, 0, 0}, sl = {0, 0, 0, 0};
                const float* hl = hlin + d8 * 256;
                for (int k = 0; k < HH; ++k) {
                    float hv = hl[k];
                    sm += hv * *(const f32x4*)(WmT + (size_t)k * 256 + q * 4);
                    sl += hv * *(const f32x4*)(WlT + (size_t)k * 256 + q * 4);
                }
                mean4 = sm + *(const f32x4*)(b_mean + q * 4);
                logv4 = sl + *(const f32x4*)(b_logv + q * 4);
                *(f32x4*)(out_mean + (size_t)dg * ZZ + q * 4) = mean4;
                *(f32x4*)(out_logv + (size_t)dg * ZZ + q * 4) = logv4;
            }
            __syncthreads();
            {
                f32x4 ep = *(const f32x4*)(eps + (size_t)dg * ZZ + q * 4);
                f32x4 zv;
#pragma unroll
                for (int m = 0; m < 4; ++m)
                    zv[m] = ep[m] * __expf(0.5f * logv4[m]) + mean4[m];
                *(f32x4*)(out_z + (size_t)dg * ZZ + q * 4) = zv;
                *(f32x4*)(hlin + d8 * 256 + q * 4) = zv;
            }
            __syncthreads();
            {
                f32x4 s = {0, 0, 0, 0};
                const float* zlp = hlin + d8 * 256;
                for (int k = 0; k < ZZ; ++k)
                    s += zlp[k] * *(const f32x4*)(WhT + (size_t)k * 256 + q * 4);
                f32x4 h0v = s + *(const f32x4*)(b_l2h + q * 4);
                __hip_atomic_store(
                    (unsigned long long*)(xh + (size_t)bi * (DD * HH) + (size_t)dg * HH + q * 4),
                    pack4h((_Float16)h0v[0], (_Float16)h0v[1],
                           (_Float16)h0v[2], (_Float16)h0v[3]),
                    __ATOMIC_RELAXED, __HIP_MEMORY_SCOPE_AGENT);
            }
            __syncthreads();
            if (tid == 0)
                __hip_atomic_store(&flags[blockIdx.x], bi + 1,
                                   __ATOMIC_RELAXED, __HIP_MEMORY_SCOPE_AGENT);
            if (tid < 64) {
                for (;;) {
                    int f = (tid < NBLK)
                          ? __hip_atomic_load(&flags[tid], __ATOMIC_RELAXED, __HIP_MEMORY_SCOPE_AGENT)
                          : 0x7fffffff;
                    if (__all(f >= bi + 1)) break;
                    __builtin_amdgcn_s_sleep(1);
                }
            }
            __syncthreads();
            {
                const _Float16* xr = xh + (size_t)bi * (DD * HH);
                f16x8 tv[8];
#pragma unroll
                for (int i = 0; i < 8; ++i) {
                    int u = tid + i * 512;
                    int chunk = u >> 6, ln = u & 63;
                    int dt = chunk >> 3, ks = chunk & 7, lg = ln >> 4, lc = ln & 15;
                    tv[i] = *(const f16x8*)(xr + (size_t)(dt * 16 + lc) * HH + ks * 32 + lg * 8);
                }
#pragma unroll
                for (int i = 0; i < 8; ++i)
                    *(f16x8*)&hpk[(size_t)(tid + i * 512) * 8] = tv[i];
            }
            __syncthreads();
            ++bi;
        }
    }
}

// ---------------- per-row logsumexp merge (one wave per row, nt <= 64) ----------------
__global__ __launch_bounds__(64) void lse_reduce(
    const float* __restrict__ pm, const float* __restrict__ ps,
    float* __restrict__ lse, int nt)
{
    int row = blockIdx.x;
    int l = threadIdx.x;
    float m = (l < nt) ? pm[(size_t)row * nt + l] : -3.0e38f;
    float s = (l < nt) ? ps[(size_t)row * nt + l] : 0.f;
    for (int mk = 1; mk <= 32; mk <<= 1) {
        float m2 = __shfl_xor(m, mk);
        float s2 = __shfl_xor(s, mk);
        float mn = fmaxf(m, m2);
        s = s * __expf(m - mn) + s2 * __expf(m2 - mn);
        m = mn;
    }
    if (l == 0) lse[row] = m + logf(s);
}

extern "C" void kernel_launch(void* const* d_in, const int* in_sizes, int n_in,
                              void* d_out, int out_size, void* d_ws, size_t ws_size,
                              hipStream_t stream)
{
    const int*           nodes     = (const int*)d_in[0];
    const unsigned char* edges_raw = (const unsigned char*)d_in[1];
    const float* emb    = (const float*)d_in[2];
    const float* ecWih  = (const float*)d_in[3];
    const float* ecWhh  = (const float*)d_in[4];
    const float* ecbih  = (const float*)d_in[5];
    const float* ecbhh  = (const float*)d_in[6];
    const float* esWih  = (const float*)d_in[7];
    const float* esWhh  = (const float*)d_in[8];
    const float* esbih  = (const float*)d_in[9];
    const float* esbhh  = (const float*)d_in[10];
    const float* dcWih  = (const float*)d_in[11];
    const float* dcWhh  = (const float*)d_in[12];
    const float* dcbih  = (const float*)d_in[13];
    const float* dcbhh  = (const float*)d_in[14];
    const float* dsWih  = (const float*)d_in[15];
    const float* dsWhh  = (const float*)d_in[16];
    const float* dsbih  = (const float*)d_in[17];
    const float* dsbhh  = (const float*)d_in[18];
    const float* W_mean = (const float*)d_in[19];
    const float* b_mean = (const float*)d_in[20];
    const float* W_logv = (const float*)d_in[21];
    const float* b_logv = (const float*)d_in[22];
    const float* W_l2h  = (const float*)d_in[23];
    const float* b_l2h  = (const float*)d_in[24];
    const float* W_out  = (const float*)d_in[25];
    const float* b_out  = (const float*)d_in[26];
    const float* enc_init = (const float*)d_in[27];
    const float* eps    = (const float*)d_in[28];

    float* out      = (float*)d_out;
    float* out_mean = out + (size_t)TT * DD * VV;
    float* out_logv = out_mean + DD * ZZ;
    float* out_z    = out_logv + DD * ZZ;
    float* gi       = out;                  // scratch in logits region: [4096][3072]

    char* ws = (char*)d_ws;
    __hip_bfloat16* outs_pk = (__hip_bfloat16*)(ws + 0);         // 2MB
    __hip_bfloat16* Ap      = (__hip_bfloat16*)(ws + 2097152);   // 2MB
    __hip_bfloat16* Wp      = (__hip_bfloat16*)(ws + 4194304);   // 16.4MB
    __hip_bfloat16* Bp_all  = (__hip_bfloat16*)(ws + 20971520);  // 1.5MB
    _Float16*       Wr      = (_Float16*)(ws + 22544384);        // 1.5MB rnn-frag Whh x4
    float*          WmT     = (float*)(ws + 24117248);           // 256KB (x3 contiguous)
    float*          pm      = (float*)(ws + 24903680);           // 800KB
    float*          ps      = (float*)(ws + 25722880);           // 800KB
    float*          lse     = (float*)(ws + 26542080);           // 16KB
    unsigned char*  ecan    = (unsigned char*)(ws + 26558464);   // 4KB
    _Float16*       xh      = (_Float16*)(ws + 26562560);        // 65 x 64KB
    int*            flags   = (int*)(ws + 30822400);             // 64B
    float*          WlT     = WmT + 65536;
    float*          WhT     = WmT + 131072;

    hipMemsetAsync(flags, 0, 64, stream);

    edge_canon_k<<<1, 256, 0, stream>>>(edges_raw, ecan);
    pack_frag<<<4000, 256, 0, stream>>>(W_out, Wp, 2000 * 8 * 64);
    pack_frag4<<<dim3(96, 4), 256, 0, stream>>>(ecWih, esWih, dcWih, dsWih, Bp_all);
    pack_wrnn4<<<dim3(96, 4), 256, 0, stream>>>(ecWhh, esWhh, dcWhh, dsWhh, Wr);
    pack_lat3<<<dim3(256, 3), 256, 0, stream>>>(W_mean, W_logv, W_l2h, WmT);
    gather_pack<<<512, 256, 0, stream>>>(nodes, emb, Ap);

    // gi[4096][3072] = emb-gather x [all 4 W_ih]^T  (into d_out scratch)
    gemm_rs<2, true, false, false, false><<<dim3(32, 6), 256, 0, stream>>>(
        Ap, Bp_all, 3072, 8, 6, nullptr, nullptr, gi, nullptr, nullptr);

    // fused recurrence: encoder -> latent -> h0 -> decoder (writes packed outs)
    rnn_fused6<<<NBLK, 512, 0, stream>>>(
        ecan, gi, Wr,
        ecbih, ecbhh, esbih, esbhh, dcbih, dcbhh, dsbih, dsbhh,
        WmT, WlT, WhT, b_mean, b_logv, b_l2h,
        enc_init, eps, out_mean, out_logv, out_z, outs_pk, xh, flags);

    // pass A: LSE partials only (no C write)
    gemm_rs<2, false, true, true, false><<<dim3(32, NTL), 256, 0, stream>>>(
        outs_pk, Wp, VV, 10, NTL, b_out, nullptr, nullptr, pm, ps);
    lse_reduce<<<4096, 64, 0, stream>>>(pm, ps, lse, NTL);
    // pass B: recompute, write logp = logits - lse
    gemm_rs<2, true, true, false, true><<<dim3(32, NTL), 256, 0, stream>>>(
        outs_pk, Wp, VV, 10, NTL, b_out, lse, out, nullptr, nullptr);
}

// Round 15
// 810.980 us; speedup vs baseline: 2.1605x; 1.1131x over previous
//
#include <hip/hip_runtime.h>
#include <hip/hip_bf16.h>

#define TT 32
#define DD 128
#define HH 256
#define VV 32000
#define ZZ 256
#define NTL 50            // n-slabs for V-GEMM (50 x 640 = 32000)
#define NBLK 16           // rnn blocks (8 j-slices x 2 variants)
#define GHLP 100          // ghl row pitch in f16 (96 + 4 pad)

typedef __attribute__((ext_vector_type(8))) short bf16x8;
typedef __attribute__((ext_vector_type(4))) float f32x4;
typedef __attribute__((ext_vector_type(8))) _Float16 f16x8;

static __device__ inline unsigned short f2bf(float x) {
    __hip_bfloat16 h = __float2bfloat16(x);
    return *(unsigned short*)&h;
}

static __device__ inline unsigned long long pack4h(_Float16 a, _Float16 b,
                                                   _Float16 c, _Float16 d) {
    union { _Float16 h[4]; unsigned long long u; } x;
    x.h[0] = a; x.h[1] = b; x.h[2] = c; x.h[3] = d;
    return x.u;
}

// async global->LDS 16B: per-lane global src, wave-uniform LDS base (+lane*16 by HW)
static __device__ inline void gload_lds16(const void* g, void* l) {
    __builtin_amdgcn_global_load_lds(
        (const __attribute__((address_space(1))) void*)g,
        (__attribute__((address_space(3))) void*)l, 16, 0, 0);
}

// ---------------- edges canonicalizer (bool-vs-int32 layout detect) ----------------
__global__ void edge_canon_k(const unsigned char* __restrict__ eb,
                             unsigned char* __restrict__ canon)
{
    __shared__ int flag;
    if (threadIdx.x == 0) flag = 0;
    __syncthreads();
    int acc = 0;
    for (int i = threadIdx.x; i < TT * DD; i += 256)
        if (i & 3) acc |= eb[i];
    if (acc) atomicOr(&flag, 1);
    __syncthreads();
    const bool is_i32 = (flag == 0);
    for (int i = threadIdx.x; i < TT * DD; i += 256)
        canon[i] = is_i32 ? eb[4 * (size_t)i] : eb[i];
}

// ---------------- pack f32 [nrow16*16][256] -> fragment-linear bf16 (W_out) ----------------
__global__ __launch_bounds__(256) void pack_frag(
    const float* __restrict__ src, __hip_bfloat16* __restrict__ dst, int nchunks_total)
{
    int i = blockIdx.x * 256 + threadIdx.x;
    if (i >= nchunks_total) return;
    int lane = i & 63, ks = (i >> 6) & 7, j = i >> 9;
    int g = lane >> 4, c = lane & 15;
    const float* s = src + (size_t)(j * 16 + c) * HH + ks * 32 + g * 8;
    float4 v0 = *(const float4*)s;
    float4 v1 = *(const float4*)(s + 4);
    bf16x8 o;
    o[0] = (short)f2bf(v0.x); o[1] = (short)f2bf(v0.y);
    o[2] = (short)f2bf(v0.z); o[3] = (short)f2bf(v0.w);
    o[4] = (short)f2bf(v1.x); o[5] = (short)f2bf(v1.y);
    o[6] = (short)f2bf(v1.z); o[7] = (short)f2bf(v1.w);
    *(bf16x8*)(dst + (size_t)i * 8) = o;
}

// ---------------- pack 4 Wih matrices -> fragment-linear bf16, slot = blockIdx.y ----------------
__global__ __launch_bounds__(256) void pack_frag4(
    const float* __restrict__ s0, const float* __restrict__ s1,
    const float* __restrict__ s2, const float* __restrict__ s3,
    __hip_bfloat16* __restrict__ dst)
{
    int i = blockIdx.x * 256 + threadIdx.x;
    if (i >= 24576) return;
    int slot = blockIdx.y;
    const float* src = (slot == 0) ? s0 : (slot == 1) ? s1 : (slot == 2) ? s2 : s3;
    __hip_bfloat16* d = dst + (size_t)slot * 196608;
    int lane = i & 63, ks = (i >> 6) & 7, j = i >> 9;
    int g = lane >> 4, c = lane & 15;
    const float* s = src + (size_t)(j * 16 + c) * HH + ks * 32 + g * 8;
    float4 v0 = *(const float4*)s;
    float4 v1 = *(const float4*)(s + 4);
    bf16x8 o;
    o[0] = (short)f2bf(v0.x); o[1] = (short)f2bf(v0.y);
    o[2] = (short)f2bf(v0.z); o[3] = (short)f2bf(v0.w);
    o[4] = (short)f2bf(v1.x); o[5] = (short)f2bf(v1.y);
    o[6] = (short)f2bf(v1.z); o[7] = (short)f2bf(v1.w);
    *(bf16x8*)(d + (size_t)i * 8) = o;
}

// ---------------- pack 4 Whh matrices -> rnn B-frag f16, slot = blockIdx.y ----------------
__global__ __launch_bounds__(256) void pack_wrnn4(
    const float* __restrict__ s0, const float* __restrict__ s1,
    const float* __restrict__ s2, const float* __restrict__ s3,
    _Float16* __restrict__ dst)
{
    int i = blockIdx.x * 256 + threadIdx.x;
    if (i >= 24576) return;
    int slot = blockIdx.y;
    const float* src = (slot == 0) ? s0 : (slot == 1) ? s1 : (slot == 2) ? s2 : s3;
    _Float16* d = dst + (size_t)slot * 196608;
    int lane = i & 63;
    int t2 = i >> 6;
    int ks = t2 & 7;
    int t3 = t2 >> 3;
    int tt = t3 % 6;
    int j8 = t3 / 6;
    int g = lane >> 4, c = lane & 15;
    int jg2 = tt / 3, gt = tt % 3;
    int srow = gt * 256 + j8 * 32 + jg2 * 16 + c;
    int scol = ks * 32 + g * 8;
    const float* s = src + (size_t)srow * HH + scol;
    float4 v0 = *(const float4*)s;
    float4 v1 = *(const float4*)(s + 4);
    f16x8 o;
    o[0] = (_Float16)v0.x; o[1] = (_Float16)v0.y;
    o[2] = (_Float16)v0.z; o[3] = (_Float16)v0.w;
    o[4] = (_Float16)v1.x; o[5] = (_Float16)v1.y;
    o[6] = (_Float16)v1.z; o[7] = (_Float16)v1.w;
    *(f16x8*)(d + (size_t)i * 8) = o;
}

// ---------------- gather emb rows by token -> packed fragment A [4096][256] ----------------
__global__ __launch_bounds__(256) void gather_pack(
    const int* __restrict__ nodes, const float* __restrict__ emb,
    __hip_bfloat16* __restrict__ dst)
{
    int i = blockIdx.x * 256 + threadIdx.x;      // 131072 chunks
    int lane = i & 63, ks = (i >> 6) & 7, j = i >> 9;
    int g = lane >> 4, c = lane & 15;
    int row = j * 16 + c;
    int tok = nodes[row];
    const float* s = emb + (size_t)tok * HH + ks * 32 + g * 8;
    float4 v0 = *(const float4*)s;
    float4 v1 = *(const float4*)(s + 4);
    bf16x8 o;
    o[0] = (short)f2bf(v0.x); o[1] = (short)f2bf(v0.y);
    o[2] = (short)f2bf(v0.z); o[3] = (short)f2bf(v0.w);
    o[4] = (short)f2bf(v1.x); o[5] = (short)f2bf(v1.y);
    o[6] = (short)f2bf(v1.z); o[7] = (short)f2bf(v1.w);
    *(bf16x8*)(dst + (size_t)i * 8) = o;
}

// ---------------- transpose 256x256 f32 x3 (latent weights), slot = blockIdx.y ----------------
__global__ __launch_bounds__(256) void pack_lat3(
    const float* __restrict__ s0, const float* __restrict__ s1,
    const float* __restrict__ s2, float* __restrict__ dst)
{
    int i = blockIdx.x * 256 + threadIdx.x;   // 65536
    int slot = blockIdx.y;
    const float* src = (slot == 0) ? s0 : (slot == 1) ? s1 : s2;
    float* d = dst + (size_t)slot * 65536;
    int j = i & 255, k = i >> 8;
    d[(size_t)k * 256 + j] = src[(size_t)j * 256 + k];
}

// ============ register-stationary GEMM, packed operands, M-doubled (for gi) ============
template<int MT, bool WRITE_C, bool HAS_BIAS, bool LSE_PARTIAL, bool LSE_SUB>
__global__ __launch_bounds__(256, 2) void gemm_rs(
    const __hip_bfloat16* __restrict__ A,
    const __hip_bfloat16* __restrict__ B,
    int ldc, int nchunks, int ntiles,
    const float* __restrict__ bias,
    const float* __restrict__ lse,
    float* __restrict__ C,
    float* __restrict__ pm, float* __restrict__ ps)
{
    __shared__ float lds_st[WRITE_C ? (4 * 16 * 68) : 1];

    const int tid  = threadIdx.x;
    const int w    = tid >> 6;
    const int lane = tid & 63;
    const int g    = lane >> 4;
    const int c    = lane & 15;
    const int m0   = blockIdx.x * (64 * MT);
    const int n0   = blockIdx.y * (nchunks * 64);
    const int jb0  = n0 >> 4;

    bf16x8 a[MT][8];
#pragma unroll
    for (int mt = 0; mt < MT; ++mt) {
        const int row16 = m0 + mt * 64 + w * 16;
        const __hip_bfloat16* ap = A + (((size_t)(row16 >> 4) * 8) * 64 + lane) * 8;
#pragma unroll
        for (int ks = 0; ks < 8; ++ks) a[mt][ks] = *(const bf16x8*)(ap + ks * 512);
    }

    float mrun[MT][4], srun[MT][4];
#pragma unroll
    for (int mt = 0; mt < MT; ++mt)
#pragma unroll
        for (int r = 0; r < 4; ++r) { mrun[mt][r] = -3.0e38f; srun[mt][r] = 0.f; }

    float lsev[MT][4];
    if (LSE_SUB) {
#pragma unroll
        for (int mt = 0; mt < MT; ++mt)
#pragma unroll
            for (int r = 0; r < 4; ++r)
                lsev[mt][r] = lse[m0 + mt * 64 + w * 16 + 4 * g + r];
    }

    for (int nc = 0; nc < nchunks; ++nc) {
        const int nb = n0 + nc * 64;
        const __hip_bfloat16* bp = B + (((size_t)(jb0 + nc * 4) * 8) * 64 + lane) * 8;

        f32x4 acc[MT][4];
#pragma unroll
        for (int mt = 0; mt < MT; ++mt)
#pragma unroll
            for (int nf = 0; nf < 4; ++nf) acc[mt][nf] = (f32x4){0.f, 0.f, 0.f, 0.f};

#pragma unroll
        for (int ks = 0; ks < 8; ++ks) {
            bf16x8 b0 = *(const bf16x8*)(bp + (0 * 8 + ks) * 512);
            bf16x8 b1 = *(const bf16x8*)(bp + (1 * 8 + ks) * 512);
            bf16x8 b2 = *(const bf16x8*)(bp + (2 * 8 + ks) * 512);
            bf16x8 b3 = *(const bf16x8*)(bp + (3 * 8 + ks) * 512);
#pragma unroll
            for (int mt = 0; mt < MT; ++mt) {
                acc[mt][0] = __builtin_amdgcn_mfma_f32_16x16x32_bf16(a[mt][ks], b0, acc[mt][0], 0, 0, 0);
                acc[mt][1] = __builtin_amdgcn_mfma_f32_16x16x32_bf16(a[mt][ks], b1, acc[mt][1], 0, 0, 0);
                acc[mt][2] = __builtin_amdgcn_mfma_f32_16x16x32_bf16(a[mt][ks], b2, acc[mt][2], 0, 0, 0);
                acc[mt][3] = __builtin_amdgcn_mfma_f32_16x16x32_bf16(a[mt][ks], b3, acc[mt][3], 0, 0, 0);
            }
        }

        float bv[4] = {0.f, 0.f, 0.f, 0.f};
        if (HAS_BIAS) {
#pragma unroll
            for (int nf = 0; nf < 4; ++nf) bv[nf] = bias[nb + nf * 16 + c];
        }

        if (LSE_PARTIAL) {
#pragma unroll
            for (int mt = 0; mt < MT; ++mt)
#pragma unroll
                for (int r = 0; r < 4; ++r) {
                    float l0 = acc[mt][0][r] + bv[0];
                    float l1 = acc[mt][1][r] + bv[1];
                    float l2 = acc[mt][2][r] + bv[2];
                    float l3 = acc[mt][3][r] + bv[3];
                    float mc = fmaxf(fmaxf(l0, l1), fmaxf(l2, l3));
                    float mn = fmaxf(mrun[mt][r], mc);
                    srun[mt][r] = srun[mt][r] * __expf(mrun[mt][r] - mn)
                            + __expf(l0 - mn) + __expf(l1 - mn)
                            + __expf(l2 - mn) + __expf(l3 - mn);
                    mrun[mt][r] = mn;
                }
        }

        if (WRITE_C) {
            const int base = w * (16 * 68);
#pragma unroll
            for (int mt = 0; mt < MT; ++mt) {
                const int row16 = m0 + mt * 64 + w * 16;
#pragma unroll
                for (int nf = 0; nf < 4; ++nf)
#pragma unroll
                    for (int r = 0; r < 4; ++r) {
                        float v = acc[mt][nf][r] + bv[nf];
                        if (LSE_SUB) v -= lsev[mt][r];
                        lds_st[base + (4 * g + r) * 68 + nf * 16 + c] = v;
                    }
#pragma unroll
                for (int i = 0; i < 4; ++i) {
                    int lr = i * 4 + g;
                    float4 v = *(const float4*)&lds_st[base + lr * 68 + c * 4];
                    *(float4*)(C + (size_t)(row16 + lr) * ldc + nb + c * 4) = v;
                }
            }
        }
    }

    if (LSE_PARTIAL) {
#pragma unroll
        for (int mt = 0; mt < MT; ++mt)
#pragma unroll
            for (int r = 0; r < 4; ++r) {
                float m = mrun[mt][r], s = srun[mt][r];
#pragma unroll
                for (int mk = 1; mk <= 8; mk <<= 1) {
                    float m2 = __shfl_xor(m, mk);
                    float s2 = __shfl_xor(s, mk);
                    float mn = fmaxf(m, m2);
                    s = s * __expf(m - mn) + s2 * __expf(m2 - mn);
                    m = mn;
                }
                if (c == 0) {
                    int row = m0 + mt * 64 + w * 16 + 4 * g + r;
                    pm[(size_t)row * ntiles + blockIdx.y] = m;
                    ps[(size_t)row * ntiles + blockIdx.y] = s;
                }
            }
    }
}

// ============ LDS-staged GEMM (passes A/B): B tiles via global_load_lds, dbuf ============
// Same math/indexing as gemm_rs<2,...>; B tile (32KB, fragment-linear = contiguous)
// staged into double-buffered LDS, one barrier per K-chunk (m97 2-phase pattern).
template<bool WRITE_C, bool HAS_BIAS, bool LSE_PARTIAL, bool LSE_SUB>
__global__ __launch_bounds__(256, 2) void gemm_ls(
    const __hip_bfloat16* __restrict__ A,
    const __hip_bfloat16* __restrict__ B,
    int ldc, int nchunks, int ntiles,
    const float* __restrict__ bias,
    const float* __restrict__ lse,
    float* __restrict__ C,
    float* __restrict__ pm, float* __restrict__ ps)
{
    __shared__ __align__(16) char ldsB[2][32768];
    __shared__ float lds_st[WRITE_C ? (4 * 16 * 68) : 1];

    const int tid  = threadIdx.x;
    const int w    = tid >> 6;
    const int lane = tid & 63;
    const int g    = lane >> 4;
    const int c    = lane & 15;
    const int m0   = blockIdx.x * 128;
    const int n0   = blockIdx.y * (nchunks * 64);
    const int jb0  = n0 >> 4;

    bf16x8 a[2][8];
#pragma unroll
    for (int mt = 0; mt < 2; ++mt) {
        const int row16 = m0 + mt * 64 + w * 16;
        const __hip_bfloat16* ap = A + (((size_t)(row16 >> 4) * 8) * 64 + lane) * 8;
#pragma unroll
        for (int ks = 0; ks < 8; ++ks) a[mt][ks] = *(const bf16x8*)(ap + ks * 512);
    }

    float mrun[2][4], srun[2][4];
#pragma unroll
    for (int mt = 0; mt < 2; ++mt)
#pragma unroll
        for (int r = 0; r < 4; ++r) { mrun[mt][r] = -3.0e38f; srun[mt][r] = 0.f; }

    float lsev[2][4];
    if (LSE_SUB) {
#pragma unroll
        for (int mt = 0; mt < 2; ++mt)
#pragma unroll
            for (int r = 0; r < 4; ++r)
                lsev[mt][r] = lse[m0 + mt * 64 + w * 16 + 4 * g + r];
    }

    // stage tile nc into buffer b: 32KB contiguous, wave w handles segments w*8..w*8+7
    const char* Bbase = (const char*)B;
#define STAGE_TILE(bbuf, nc_)                                                     \
    {                                                                             \
        const char* src = Bbase + ((size_t)(jb0 + (nc_) * 4) * 8 * 64) * 16;      \
        _Pragma("unroll")                                                         \
        for (int i_ = 0; i_ < 8; ++i_) {                                          \
            int seg = w * 8 + i_;                                                 \
            gload_lds16(src + (size_t)seg * 1024 + lane * 16,                     \
                        &ldsB[bbuf][seg * 1024]);                                 \
        }                                                                         \
    }

    int buf = 0;
    STAGE_TILE(0, 0);
    __syncthreads();

    for (int nc = 0; nc < nchunks; ++nc) {
        if (nc + 1 < nchunks) STAGE_TILE(buf ^ 1, nc + 1);

        const int nb = n0 + nc * 64;
        f32x4 acc[2][4];
#pragma unroll
        for (int mt = 0; mt < 2; ++mt)
#pragma unroll
            for (int nf = 0; nf < 4; ++nf) acc[mt][nf] = (f32x4){0.f, 0.f, 0.f, 0.f};

#pragma unroll
        for (int ks = 0; ks < 8; ++ks) {
            bf16x8 b0 = *(const bf16x8*)&ldsB[buf][((0 * 8 + ks) * 64 + lane) * 16];
            bf16x8 b1 = *(const bf16x8*)&ldsB[buf][((1 * 8 + ks) * 64 + lane) * 16];
            bf16x8 b2 = *(const bf16x8*)&ldsB[buf][((2 * 8 + ks) * 64 + lane) * 16];
            bf16x8 b3 = *(const bf16x8*)&ldsB[buf][((3 * 8 + ks) * 64 + lane) * 16];
#pragma unroll
            for (int mt = 0; mt < 2; ++mt) {
                acc[mt][0] = __builtin_amdgcn_mfma_f32_16x16x32_bf16(a[mt][ks], b0, acc[mt][0], 0, 0, 0);
                acc[mt][1] = __builtin_amdgcn_mfma_f32_16x16x32_bf16(a[mt][ks], b1, acc[mt][1], 0, 0, 0);
                acc[mt][2] = __builtin_amdgcn_mfma_f32_16x16x32_bf16(a[mt][ks], b2, acc[mt][2], 0, 0, 0);
                acc[mt][3] = __builtin_amdgcn_mfma_f32_16x16x32_bf16(a[mt][ks], b3, acc[mt][3], 0, 0, 0);
            }
        }

        float bv[4] = {0.f, 0.f, 0.f, 0.f};
        if (HAS_BIAS) {
#pragma unroll
            for (int nf = 0; nf < 4; ++nf) bv[nf] = bias[nb + nf * 16 + c];
        }

        if (LSE_PARTIAL) {
#pragma unroll
            for (int mt = 0; mt < 2; ++mt)
#pragma unroll
                for (int r = 0; r < 4; ++r) {
                    float l0 = acc[mt][0][r] + bv[0];
                    float l1 = acc[mt][1][r] + bv[1];
                    float l2 = acc[mt][2][r] + bv[2];
                    float l3 = acc[mt][3][r] + bv[3];
                    float mc = fmaxf(fmaxf(l0, l1), fmaxf(l2, l3));
                    float mn = fmaxf(mrun[mt][r], mc);
                    srun[mt][r] = srun[mt][r] * __expf(mrun[mt][r] - mn)
                            + __expf(l0 - mn) + __expf(l1 - mn)
                            + __expf(l2 - mn) + __expf(l3 - mn);
                    mrun[mt][r] = mn;
                }
        }

        if (WRITE_C) {
            const int base = w * (16 * 68);
#pragma unroll
            for (int mt = 0; mt < 2; ++mt) {
                const int row16 = m0 + mt * 64 + w * 16;
#pragma unroll
                for (int nf = 0; nf < 4; ++nf)
#pragma unroll
                    for (int r = 0; r < 4; ++r) {
                        float v = acc[mt][nf][r] + bv[nf];
                        if (LSE_SUB) v -= lsev[mt][r];
                        lds_st[base + (4 * g + r) * 68 + nf * 16 + c] = v;
                    }
                // wave-private restage: no barrier needed
#pragma unroll
                for (int i = 0; i < 4; ++i) {
                    int lr = i * 4 + g;
                    float4 v = *(const float4*)&lds_st[base + lr * 68 + c * 4];
                    *(float4*)(C + (size_t)(row16 + lr) * ldc + nb + c * 4) = v;
                }
            }
        }

        __syncthreads();   // drains vmcnt (next tile staged) + protects buf reuse
        buf ^= 1;
    }
#undef STAGE_TILE

    if (LSE_PARTIAL) {
#pragma unroll
        for (int mt = 0; mt < 2; ++mt)
#pragma unroll
            for (int r = 0; r < 4; ++r) {
                float m = mrun[mt][r], s = srun[mt][r];
#pragma unroll
                for (int mk = 1; mk <= 8; mk <<= 1) {
                    float m2 = __shfl_xor(m, mk);
                    float s2 = __shfl_xor(s, mk);
                    float mn = fmaxf(m, m2);
                    s = s * __expf(m - mn) + s2 * __expf(m2 - mn);
                    m = mn;
                }
                if (c == 0) {
                    int row = m0 + mt * 64 + w * 16 + 4 * g + r;
                    pm[(size_t)row * ntiles + blockIdx.y] = m;
                    ps[(size_t)row * ntiles + blockIdx.y] = s;
                }
            }
    }
}

// ============ fused recurrence v6 (proven): batched staging, 8B exchange, flag barrier ============
__global__ __launch_bounds__(512) void rnn_fused6(
    const unsigned char* __restrict__ ecan,
    const float* __restrict__ gi,          // [4096][3072]
    const _Float16* __restrict__ Wr,       // [4 slots][8 j8][6 tt][8 ks][64][8]
    const float* __restrict__ ecbih, const float* __restrict__ ecbhh,
    const float* __restrict__ esbih, const float* __restrict__ esbhh,
    const float* __restrict__ dcbih, const float* __restrict__ dcbhh,
    const float* __restrict__ dsbih, const float* __restrict__ dsbhh,
    const float* __restrict__ WmT, const float* __restrict__ WlT,
    const float* __restrict__ WhT,
    const float* __restrict__ b_mean, const float* __restrict__ b_logv,
    const float* __restrict__ b_l2h,
    const float* __restrict__ enc_init, const float* __restrict__ eps,
    float* __restrict__ out_mean, float* __restrict__ out_logv,
    float* __restrict__ out_z,
    __hip_bfloat16* __restrict__ outs_pk,
    _Float16* __restrict__ xh,             // [65][128][256] f16, write-once slots
    int* __restrict__ flags)               // [16]
{
    __shared__ _Float16 wlds[6 * 8 * 64 * 8];   // 48K
    __shared__ _Float16 hpk[64 * 64 * 8];       // 64K, A-frag layout of h
    __shared__ _Float16 ghl[DD * GHLP];         // 25K: gh tile [128][96+pad]
    __shared__ float    bsum[4 * 256];          // 4K: br,bz,bin,bhn
    __shared__ unsigned char ecan_l[TT * DD];   // 4K

    const int v   = blockIdx.x & 1;             // 0: child (e!=0), 1: sibling
    const int j8  = blockIdx.x >> 1;
    const int tid = threadIdx.x;
    const int w    = tid >> 6;
    const int lane = tid & 63;
    const int g    = lane >> 4;
    const int c    = lane & 15;
    const int dq   = w & 3;
    const int jg2  = w >> 2;

    for (int u = tid; u < TT * DD; u += 512) ecan_l[u] = ecan[u];

    // ---- init hpk from enc_init ----
    for (int u = tid; u < 4096; u += 512) {
        int chunk = u >> 6, ln = u & 63;
        int dt = chunk >> 3, ks = chunk & 7, lg = ln >> 4, lc = ln & 15;
        const float* s = enc_init + (size_t)(dt * 16 + lc) * HH + ks * 32 + lg * 8;
        float4 v0 = *(const float4*)s;
        float4 v1 = *(const float4*)(s + 4);
        f16x8 o;
        o[0] = (_Float16)v0.x; o[1] = (_Float16)v0.y;
        o[2] = (_Float16)v0.z; o[3] = (_Float16)v0.w;
        o[4] = (_Float16)v1.x; o[5] = (_Float16)v1.y;
        o[6] = (_Float16)v1.z; o[7] = (_Float16)v1.w;
        *(f16x8*)&hpk[(size_t)u * 8] = o;
    }
    __syncthreads();

    int bi = 0;   // barrier index == xh slot

    for (int p = 0; p < 2; ++p) {
        // ---- weights + biases into LDS, once per phase ----
        {
            const _Float16* wsrc = Wr + ((size_t)(p * 2 + v) * 8 + j8) * (3072 * 8);
            for (int idx = tid; idx < 3072; idx += 512)
                *(f16x8*)&wlds[(size_t)idx * 8] = *(const f16x8*)(wsrc + (size_t)idx * 8);
        }
        {
            const float* bih = p ? (v ? dsbih : dcbih) : (v ? esbih : ecbih);
            const float* bhh = p ? (v ? dsbhh : dcbhh) : (v ? esbhh : ecbhh);
            if (tid < 256) {
                bsum[tid]       = bih[tid]       + bhh[tid];
                bsum[256 + tid] = bih[256 + tid] + bhh[256 + tid];
                bsum[512 + tid] = bih[512 + tid];
                bsum[768 + tid] = bhh[512 + tid];
            }
        }
        __syncthreads();

        for (int st = 0; st < TT; ++st) {
            // ---- gi prefetch for this step's gate units ----
            f32x4 gpr0[3], gpr1[3];
            bool sel0, sel1;
            {
                const int u0 = tid, u1 = tid + 512;
                const int d0 = u0 >> 3, d1 = u1 >> 3;
                const int jgA = j8 * 32 + (u0 & 7) * 4;
                const int jgB = j8 * 32 + (u1 & 7) * 4;
                sel0 = (ecan_l[st * DD + d0] != 0) == (v == 0);
                sel1 = (ecan_l[st * DD + d1] != 0) == (v == 0);
                if (sel0) {
                    const float* gp = gi + (size_t)(st * DD + d0) * 3072 + p * 1536 + v * 768 + jgA;
                    gpr0[0] = *(const f32x4*)gp;
                    gpr0[1] = *(const f32x4*)(gp + 256);
                    gpr0[2] = *(const f32x4*)(gp + 512);
                }
                if (sel1) {
                    const float* gp = gi + (size_t)(st * DD + d1) * 3072 + p * 1536 + v * 768 + jgB;
                    gpr1[0] = *(const f32x4*)gp;
                    gpr1[1] = *(const f32x4*)(gp + 256);
                    gpr1[2] = *(const f32x4*)(gp + 512);
                }
            }

            // ---- MFMA: acc[dti][gate] from LDS h x LDS W ----
            f32x4 acc[2][3];
#pragma unroll
            for (int a = 0; a < 2; ++a)
#pragma unroll
                for (int b = 0; b < 3; ++b) acc[a][b] = (f32x4){0.f, 0.f, 0.f, 0.f};
#pragma unroll
            for (int ks = 0; ks < 8; ++ks) {
                f16x8 a0 = *(const f16x8*)&hpk[(((dq * 2 + 0) * 8 + ks) * 64 + lane) * 8];
                f16x8 a1 = *(const f16x8*)&hpk[(((dq * 2 + 1) * 8 + ks) * 64 + lane) * 8];
#pragma unroll
                for (int gt = 0; gt < 3; ++gt) {
                    f16x8 bf = *(const f16x8*)&wlds[(((jg2 * 3 + gt) * 8 + ks) * 64 + lane) * 8];
                    acc[0][gt] = __builtin_amdgcn_mfma_f32_16x16x32_f16(a0, bf, acc[0][gt], 0, 0, 0);
                    acc[1][gt] = __builtin_amdgcn_mfma_f32_16x16x32_f16(a1, bf, acc[1][gt], 0, 0, 0);
                }
            }

            // ---- acc -> ghl (f16) ----
#pragma unroll
            for (int dti = 0; dti < 2; ++dti) {
                const int dt = dq * 2 + dti;
#pragma unroll
                for (int gt = 0; gt < 3; ++gt)
#pragma unroll
                    for (int rr = 0; rr < 4; ++rr)
                        ghl[(dt * 16 + 4 * g + rr) * GHLP + gt * 32 + jg2 * 16 + c] =
                            (_Float16)acc[dti][gt][rr];
            }
            __syncthreads();

            // ---- gate: 2 units/thread, unit = (d, 4 consecutive j) ----
            _Float16* xcur = xh + (size_t)bi * (DD * HH);
#pragma unroll
            for (int uu = 0; uu < 2; ++uu) {
                const bool sel = uu ? sel1 : sel0;
                if (!sel) continue;
                const int u = tid + uu * 512;
                const int d = u >> 3, jq = u & 7;
                const int jl = jq * 4;
                const int jg_ = j8 * 32 + jl;
                const f32x4* gpr = uu ? gpr1 : gpr0;

                f32x4 br  = *(const f32x4*)&bsum[jg_];
                f32x4 bz  = *(const f32x4*)&bsum[256 + jg_];
                f32x4 bni = *(const f32x4*)&bsum[512 + jg_];
                f32x4 bnh = *(const f32x4*)&bsum[768 + jg_];
                const _Float16* gd = &ghl[d * GHLP];
                const int dt = d >> 4, lc = d & 15, ks = jg_ >> 5, lg = (jg_ >> 3) & 3;
                const int ch = ((dt * 8 + ks) * 64 + lg * 16 + lc);
                const _Float16* hop = &hpk[(size_t)ch * 8 + (jg_ & 7)];

                _Float16 hn[4];
                unsigned short ob[4];
#pragma unroll
                for (int m = 0; m < 4; ++m) {
                    float ghr = (float)gd[jl + m];
                    float ghz = (float)gd[32 + jl + m];
                    float ghn = (float)gd[64 + jl + m];
                    float rg = 1.f / (1.f + __expf(-(gpr[0][m] + br[m] + ghr)));
                    float zg = 1.f / (1.f + __expf(-(gpr[1][m] + bz[m] + ghz)));
                    float nn = tanhf(gpr[2][m] + bni[m] + rg * (ghn + bnh[m]));
                    float hv = (1.f - zg) * nn + zg * (float)hop[m];
                    hn[m] = (_Float16)hv;
                    ob[m] = f2bf(hv);
                }
                __hip_atomic_store((unsigned long long*)(xcur + (size_t)d * HH + jg_),
                                   pack4h(hn[0], hn[1], hn[2], hn[3]),
                                   __ATOMIC_RELAXED, __HIP_MEMORY_SCOPE_AGENT);
                if (p) {
                    union { unsigned short s[4]; unsigned long long u; } ou;
                    ou.s[0] = ob[0]; ou.s[1] = ob[1]; ou.s[2] = ob[2]; ou.s[3] = ob[3];
                    size_t och = ((size_t)(st * 8 + dt) * 8 + ks) * 64 + lg * 16 + lc;
                    *(unsigned long long*)((unsigned short*)outs_pk + och * 8 + (jg_ & 7)) = ou.u;
                }
            }
            __syncthreads();   // drains all waves' stores

            // ---- flag barrier ----
            if (tid == 0)
                __hip_atomic_store(&flags[blockIdx.x], bi + 1,
                                   __ATOMIC_RELAXED, __HIP_MEMORY_SCOPE_AGENT);
            if (tid < 64) {
                for (;;) {
                    int f = (tid < NBLK)
                          ? __hip_atomic_load(&flags[tid], __ATOMIC_RELAXED, __HIP_MEMORY_SCOPE_AGENT)
                          : 0x7fffffff;
                    if (__all(f >= bi + 1)) break;
                    __builtin_amdgcn_s_sleep(1);
                }
            }
            __syncthreads();

            // ---- staging: batched 8x16B loads -> hpk ----
            {
                const _Float16* xr = xh + (size_t)bi * (DD * HH);
                f16x8 tv[8];
#pragma unroll
                for (int i = 0; i < 8; ++i) {
                    int u = tid + i * 512;
                    int chunk = u >> 6, ln = u & 63;
                    int dt = chunk >> 3, ks = chunk & 7, lg = ln >> 4, lc = ln & 15;
                    tv[i] = *(const f16x8*)(xr + (size_t)(dt * 16 + lc) * HH + ks * 32 + lg * 8);
                }
#pragma unroll
                for (int i = 0; i < 8; ++i)
                    *(f16x8*)&hpk[(size_t)(tid + i * 512) * 8] = tv[i];
            }
            __syncthreads();
            ++bi;
        }

        if (p == 0) {
            // ---- latent head, d-sharded (8 rows per block) ----
            float* hlin = (float*)ghl;          // reuse ghl (needs 8KB)
            const int d8 = tid >> 6;
            const int q  = tid & 63;
            const int dg = blockIdx.x * 8 + d8;
            for (int u = tid; u < 2048; u += 512) {
                int du = u >> 8, k = u & 255;
                int d = blockIdx.x * 8 + du;
                hlin[du * 256 + k] = (float)hpk[(((size_t)(d >> 4) * 8 + (k >> 5)) * 64
                                      + ((k >> 3) & 3) * 16 + (d & 15)) * 8 + (k & 7)];
            }
            __syncthreads();
            f32x4 mean4, logv4;
            {
                f32x4 sm = {0, 0, 0, 0}, sl = {0, 0, 0, 0};
                const float* hl = hlin + d8 * 256;
                for (int k = 0; k < HH; ++k) {
                    float hv = hl[k];
                    sm += hv * *(const f32x4*)(WmT + (size_t)k * 256 + q * 4);
                    sl += hv * *(const f32x4*)(WlT + (size_t)k * 256 + q * 4);
                }
                mean4 = sm + *(const f32x4*)(b_mean + q * 4);
                logv4 = sl + *(const f32x4*)(b_logv + q * 4);
                *(f32x4*)(out_mean + (size_t)dg * ZZ + q * 4) = mean4;
                *(f32x4*)(out_logv + (size_t)dg * ZZ + q * 4) = logv4;
            }
            __syncthreads();
            {
                f32x4 ep = *(const f32x4*)(eps + (size_t)dg * ZZ + q * 4);
                f32x4 zv;
#pragma unroll
                for (int m = 0; m < 4; ++m)
                    zv[m] = ep[m] * __expf(0.5f * logv4[m]) + mean4[m];
                *(f32x4*)(out_z + (size_t)dg * ZZ + q * 4) = zv;
                *(f32x4*)(hlin + d8 * 256 + q * 4) = zv;
            }
            __syncthreads();
            {
                f32x4 s = {0, 0, 0, 0};
                const float* zlp = hlin + d8 * 256;
                for (int k = 0; k < ZZ; ++k)
                    s += zlp[k] * *(const f32x4*)(WhT + (size_t)k * 256 + q * 4);
                f32x4 h0v = s + *(const f32x4*)(b_l2h + q * 4);
                __hip_atomic_store(
                    (unsigned long long*)(xh + (size_t)bi * (DD * HH) + (size_t)dg * HH + q * 4),
                    pack4h((_Float16)h0v[0], (_Float16)h0v[1],
                           (_Float16)h0v[2], (_Float16)h0v[3]),
                    __ATOMIC_RELAXED, __HIP_MEMORY_SCOPE_AGENT);
            }
            __syncthreads();
            if (tid == 0)
                __hip_atomic_store(&flags[blockIdx.x], bi + 1,
                                   __ATOMIC_RELAXED, __HIP_MEMORY_SCOPE_AGENT);
            if (tid < 64) {
                for (;;) {
                    int f = (tid < NBLK)
                          ? __hip_atomic_load(&flags[tid], __ATOMIC_RELAXED, __HIP_MEMORY_SCOPE_AGENT)
                          : 0x7fffffff;
                    if (__all(f >= bi + 1)) break;
                    __builtin_amdgcn_s_sleep(1);
                }
            }
            __syncthreads();
            {
                const _Float16* xr = xh + (size_t)bi * (DD * HH);
                f16x8 tv[8];
#pragma unroll
                for (int i = 0; i < 8; ++i) {
                    int u = tid + i * 512;
                    int chunk = u >> 6, ln = u & 63;
                    int dt = chunk >> 3, ks = chunk & 7, lg = ln >> 4, lc = ln & 15;
                    tv[i] = *(const f16x8*)(xr + (size_t)(dt * 16 + lc) * HH + ks * 32 + lg * 8);
                }
#pragma unroll
                for (int i = 0; i < 8; ++i)
                    *(f16x8*)&hpk[(size_t)(tid + i * 512) * 8] = tv[i];
            }
            __syncthreads();
            ++bi;
        }
    }
}

// ---------------- per-row logsumexp merge (one wave per row, nt <= 64) ----------------
__global__ __launch_bounds__(64) void lse_reduce(
    const float* __restrict__ pm, const float* __restrict__ ps,
    float* __restrict__ lse, int nt)
{
    int row = blockIdx.x;
    int l = threadIdx.x;
    float m = (l < nt) ? pm[(size_t)row * nt + l] : -3.0e38f;
    float s = (l < nt) ? ps[(size_t)row * nt + l] : 0.f;
    for (int mk = 1; mk <= 32; mk <<= 1) {
        float m2 = __shfl_xor(m, mk);
        float s2 = __shfl_xor(s, mk);
        float mn = fmaxf(m, m2);
        s = s * __expf(m - mn) + s2 * __expf(m2 - mn);
        m = mn;
    }
    if (l == 0) lse[row] = m + logf(s);
}

extern "C" void kernel_launch(void* const* d_in, const int* in_sizes, int n_in,
                              void* d_out, int out_size, void* d_ws, size_t ws_size,
                              hipStream_t stream)
{
    const int*           nodes     = (const int*)d_in[0];
    const unsigned char* edges_raw = (const unsigned char*)d_in[1];
    const float* emb    = (const float*)d_in[2];
    const float* ecWih  = (const float*)d_in[3];
    const float* ecWhh  = (const float*)d_in[4];
    const float* ecbih  = (const float*)d_in[5];
    const float* ecbhh  = (const float*)d_in[6];
    const float* esWih  = (const float*)d_in[7];
    const float* esWhh  = (const float*)d_in[8];
    const float* esbih  = (const float*)d_in[9];
    const float* esbhh  = (const float*)d_in[10];
    const float* dcWih  = (const float*)d_in[11];
    const float* dcWhh  = (const float*)d_in[12];
    const float* dcbih  = (const float*)d_in[13];
    const float* dcbhh  = (const float*)d_in[14];
    const float* dsWih  = (const float*)d_in[15];
    const float* dsWhh  = (const float*)d_in[16];
    const float* dsbih  = (const float*)d_in[17];
    const float* dsbhh  = (const float*)d_in[18];
    const float* W_mean = (const float*)d_in[19];
    const float* b_mean = (const float*)d_in[20];
    const float* W_logv = (const float*)d_in[21];
    const float* b_logv = (const float*)d_in[22];
    const float* W_l2h  = (const float*)d_in[23];
    const float* b_l2h  = (const float*)d_in[24];
    const float* W_out  = (const float*)d_in[25];
    const float* b_out  = (const float*)d_in[26];
    const float* enc_init = (const float*)d_in[27];
    const float* eps    = (const float*)d_in[28];

    float* out      = (float*)d_out;
    float* out_mean = out + (size_t)TT * DD * VV;
    float* out_logv = out_mean + DD * ZZ;
    float* out_z    = out_logv + DD * ZZ;
    float* gi       = out;                  // scratch in logits region: [4096][3072]

    char* ws = (char*)d_ws;
    __hip_bfloat16* outs_pk = (__hip_bfloat16*)(ws + 0);         // 2MB
    __hip_bfloat16* Ap      = (__hip_bfloat16*)(ws + 2097152);   // 2MB
    __hip_bfloat16* Wp      = (__hip_bfloat16*)(ws + 4194304);   // 16.4MB
    __hip_bfloat16* Bp_all  = (__hip_bfloat16*)(ws + 20971520);  // 1.5MB
    _Float16*       Wr      = (_Float16*)(ws + 22544384);        // 1.5MB rnn-frag Whh x4
    float*          WmT     = (float*)(ws + 24117248);           // 256KB (x3 contiguous)
    float*          pm      = (float*)(ws + 24903680);           // 800KB
    float*          ps      = (float*)(ws + 25722880);           // 800KB
    float*          lse     = (float*)(ws + 26542080);           // 16KB
    unsigned char*  ecan    = (unsigned char*)(ws + 26558464);   // 4KB
    _Float16*       xh      = (_Float16*)(ws + 26562560);        // 65 x 64KB
    int*            flags   = (int*)(ws + 30822400);             // 64B
    float*          WlT     = WmT + 65536;
    float*          WhT     = WmT + 131072;

    hipMemsetAsync(flags, 0, 64, stream);

    edge_canon_k<<<1, 256, 0, stream>>>(edges_raw, ecan);
    pack_frag<<<4000, 256, 0, stream>>>(W_out, Wp, 2000 * 8 * 64);
    pack_frag4<<<dim3(96, 4), 256, 0, stream>>>(ecWih, esWih, dcWih, dsWih, Bp_all);
    pack_wrnn4<<<dim3(96, 4), 256, 0, stream>>>(ecWhh, esWhh, dcWhh, dsWhh, Wr);
    pack_lat3<<<dim3(256, 3), 256, 0, stream>>>(W_mean, W_logv, W_l2h, WmT);
    gather_pack<<<512, 256, 0, stream>>>(nodes, emb, Ap);

    // gi[4096][3072] = emb-gather x [all 4 W_ih]^T  (into d_out scratch)
    gemm_rs<2, true, false, false, false><<<dim3(32, 6), 256, 0, stream>>>(
        Ap, Bp_all, 3072, 8, 6, nullptr, nullptr, gi, nullptr, nullptr);

    // fused recurrence: encoder -> latent -> h0 -> decoder (writes packed outs)
    rnn_fused6<<<NBLK, 512, 0, stream>>>(
        ecan, gi, Wr,
        ecbih, ecbhh, esbih, esbhh, dcbih, dcbhh, dsbih, dsbhh,
        WmT, WlT, WhT, b_mean, b_logv, b_l2h,
        enc_init, eps, out_mean, out_logv, out_z, outs_pk, xh, flags);

    // pass A: LSE partials only (LDS-staged B, no C write)
    gemm_ls<false, true, true, false><<<dim3(32, NTL), 256, 0, stream>>>(
        outs_pk, Wp, VV, 10, NTL, b_out, nullptr, nullptr, pm, ps);
    lse_reduce<<<4096, 64, 0, stream>>>(pm, ps, lse, NTL);
    // pass B: recompute, write logp = logits - lse (LDS-staged B)
    gemm_ls<true, true, false, true><<<dim3(32, NTL), 256, 0, stream>>>(
        outs_pk, Wp, VV, 10, NTL, b_out, lse, out, nullptr, nullptr);
}

// Round 16
// 759.672 us; speedup vs baseline: 2.3064x; 1.0675x over previous
//
#include <hip/hip_runtime.h>
#include <hip/hip_bf16.h>

#define TT 32
#define DD 128
#define HH 256
#define VV 32000
#define ZZ 256
#define NTL 50            // n-slabs for V-GEMM (50 x 640 = 32000)
#define NBLK 16           // rnn blocks (8 j-slices x 2 variants)
#define NPACK 2000        // extra blocks in rnn launch that pack W_out
#define GHLP 100          // ghl row pitch in f16 (96 + 4 pad)

typedef __attribute__((ext_vector_type(8))) short bf16x8;
typedef __attribute__((ext_vector_type(4))) float f32x4;
typedef __attribute__((ext_vector_type(8))) _Float16 f16x8;

static __device__ inline unsigned short f2bf(float x) {
    __hip_bfloat16 h = __float2bfloat16(x);
    return *(unsigned short*)&h;
}

static __device__ inline unsigned long long pack4h(_Float16 a, _Float16 b,
                                                   _Float16 c, _Float16 d) {
    union { _Float16 h[4]; unsigned long long u; } x;
    x.h[0] = a; x.h[1] = b; x.h[2] = c; x.h[3] = d;
    return x.u;
}

// async global->LDS 16B: per-lane global src, wave-uniform LDS base (+lane*16 by HW)
static __device__ inline void gload_lds16(const void* g, void* l) {
    __builtin_amdgcn_global_load_lds(
        (const __attribute__((address_space(1))) void*)g,
        (__attribute__((address_space(3))) void*)l, 16, 0, 0);
}

// ---------------- edges canonicalizer (bool-vs-int32 layout detect) ----------------
__global__ void edge_canon_k(const unsigned char* __restrict__ eb,
                             unsigned char* __restrict__ canon)
{
    __shared__ int flag;
    if (threadIdx.x == 0) flag = 0;
    __syncthreads();
    int acc = 0;
    for (int i = threadIdx.x; i < TT * DD; i += 256)
        if (i & 3) acc |= eb[i];
    if (acc) atomicOr(&flag, 1);
    __syncthreads();
    const bool is_i32 = (flag == 0);
    for (int i = threadIdx.x; i < TT * DD; i += 256)
        canon[i] = is_i32 ? eb[4 * (size_t)i] : eb[i];
}

// ---------------- pack 4 Wih matrices -> fragment-linear bf16, slot = blockIdx.y ----------------
__global__ __launch_bounds__(256) void pack_frag4(
    const float* __restrict__ s0, const float* __restrict__ s1,
    const float* __restrict__ s2, const float* __restrict__ s3,
    __hip_bfloat16* __restrict__ dst)
{
    int i = blockIdx.x * 256 + threadIdx.x;
    if (i >= 24576) return;
    int slot = blockIdx.y;
    const float* src = (slot == 0) ? s0 : (slot == 1) ? s1 : (slot == 2) ? s2 : s3;
    __hip_bfloat16* d = dst + (size_t)slot * 196608;
    int lane = i & 63, ks = (i >> 6) & 7, j = i >> 9;
    int g = lane >> 4, c = lane & 15;
    const float* s = src + (size_t)(j * 16 + c) * HH + ks * 32 + g * 8;
    float4 v0 = *(const float4*)s;
    float4 v1 = *(const float4*)(s + 4);
    bf16x8 o;
    o[0] = (short)f2bf(v0.x); o[1] = (short)f2bf(v0.y);
    o[2] = (short)f2bf(v0.z); o[3] = (short)f2bf(v0.w);
    o[4] = (short)f2bf(v1.x); o[5] = (short)f2bf(v1.y);
    o[6] = (short)f2bf(v1.z); o[7] = (short)f2bf(v1.w);
    *(bf16x8*)(d + (size_t)i * 8) = o;
}

// ---------------- pack 4 Whh matrices -> rnn B-frag f16, slot = blockIdx.y ----------------
__global__ __launch_bounds__(256) void pack_wrnn4(
    const float* __restrict__ s0, const float* __restrict__ s1,
    const float* __restrict__ s2, const float* __restrict__ s3,
    _Float16* __restrict__ dst)
{
    int i = blockIdx.x * 256 + threadIdx.x;
    if (i >= 24576) return;
    int slot = blockIdx.y;
    const float* src = (slot == 0) ? s0 : (slot == 1) ? s1 : (slot == 2) ? s2 : s3;
    _Float16* d = dst + (size_t)slot * 196608;
    int lane = i & 63;
    int t2 = i >> 6;
    int ks = t2 & 7;
    int t3 = t2 >> 3;
    int tt = t3 % 6;
    int j8 = t3 / 6;
    int g = lane >> 4, c = lane & 15;
    int jg2 = tt / 3, gt = tt % 3;
    int srow = gt * 256 + j8 * 32 + jg2 * 16 + c;
    int scol = ks * 32 + g * 8;
    const float* s = src + (size_t)srow * HH + scol;
    float4 v0 = *(const float4*)s;
    float4 v1 = *(const float4*)(s + 4);
    f16x8 o;
    o[0] = (_Float16)v0.x; o[1] = (_Float16)v0.y;
    o[2] = (_Float16)v0.z; o[3] = (_Float16)v0.w;
    o[4] = (_Float16)v1.x; o[5] = (_Float16)v1.y;
    o[6] = (_Float16)v1.z; o[7] = (_Float16)v1.w;
    *(f16x8*)(d + (size_t)i * 8) = o;
}

// ---------------- gather emb rows by token -> packed fragment A [4096][256] ----------------
__global__ __launch_bounds__(256) void gather_pack(
    const int* __restrict__ nodes, const float* __restrict__ emb,
    __hip_bfloat16* __restrict__ dst)
{
    int i = blockIdx.x * 256 + threadIdx.x;      // 131072 chunks
    int lane = i & 63, ks = (i >> 6) & 7, j = i >> 9;
    int g = lane >> 4, c = lane & 15;
    int row = j * 16 + c;
    int tok = nodes[row];
    const float* s = emb + (size_t)tok * HH + ks * 32 + g * 8;
    float4 v0 = *(const float4*)s;
    float4 v1 = *(const float4*)(s + 4);
    bf16x8 o;
    o[0] = (short)f2bf(v0.x); o[1] = (short)f2bf(v0.y);
    o[2] = (short)f2bf(v0.z); o[3] = (short)f2bf(v0.w);
    o[4] = (short)f2bf(v1.x); o[5] = (short)f2bf(v1.y);
    o[6] = (short)f2bf(v1.z); o[7] = (short)f2bf(v1.w);
    *(bf16x8*)(dst + (size_t)i * 8) = o;
}

// ---------------- transpose 256x256 f32 x3 (latent weights), slot = blockIdx.y ----------------
__global__ __launch_bounds__(256) void pack_lat3(
    const float* __restrict__ s0, const float* __restrict__ s1,
    const float* __restrict__ s2, float* __restrict__ dst)
{
    int i = blockIdx.x * 256 + threadIdx.x;   // 65536
    int slot = blockIdx.y;
    const float* src = (slot == 0) ? s0 : (slot == 1) ? s1 : s2;
    float* d = dst + (size_t)slot * 65536;
    int j = i & 255, k = i >> 8;
    d[(size_t)k * 256 + j] = src[(size_t)j * 256 + k];
}

// ============ register-stationary GEMM, packed operands, M-doubled (for gi) ============
template<int MT, bool WRITE_C, bool HAS_BIAS, bool LSE_PARTIAL, bool LSE_SUB>
__global__ __launch_bounds__(256, 2) void gemm_rs(
    const __hip_bfloat16* __restrict__ A,
    const __hip_bfloat16* __restrict__ B,
    int ldc, int nchunks, int ntiles,
    const float* __restrict__ bias,
    const float* __restrict__ lse,
    float* __restrict__ C,
    float* __restrict__ pm, float* __restrict__ ps)
{
    __shared__ float lds_st[WRITE_C ? (4 * 16 * 68) : 1];

    const int tid  = threadIdx.x;
    const int w    = tid >> 6;
    const int lane = tid & 63;
    const int g    = lane >> 4;
    const int c    = lane & 15;
    const int m0   = blockIdx.x * (64 * MT);
    const int n0   = blockIdx.y * (nchunks * 64);
    const int jb0  = n0 >> 4;

    bf16x8 a[MT][8];
#pragma unroll
    for (int mt = 0; mt < MT; ++mt) {
        const int row16 = m0 + mt * 64 + w * 16;
        const __hip_bfloat16* ap = A + (((size_t)(row16 >> 4) * 8) * 64 + lane) * 8;
#pragma unroll
        for (int ks = 0; ks < 8; ++ks) a[mt][ks] = *(const bf16x8*)(ap + ks * 512);
    }

    float mrun[MT][4], srun[MT][4];
#pragma unroll
    for (int mt = 0; mt < MT; ++mt)
#pragma unroll
        for (int r = 0; r < 4; ++r) { mrun[mt][r] = -3.0e38f; srun[mt][r] = 0.f; }

    float lsev[MT][4];
    if (LSE_SUB) {
#pragma unroll
        for (int mt = 0; mt < MT; ++mt)
#pragma unroll
            for (int r = 0; r < 4; ++r)
                lsev[mt][r] = lse[m0 + mt * 64 + w * 16 + 4 * g + r];
    }

    for (int nc = 0; nc < nchunks; ++nc) {
        const int nb = n0 + nc * 64;
        const __hip_bfloat16* bp = B + (((size_t)(jb0 + nc * 4) * 8) * 64 + lane) * 8;

        f32x4 acc[MT][4];
#pragma unroll
        for (int mt = 0; mt < MT; ++mt)
#pragma unroll
            for (int nf = 0; nf < 4; ++nf) acc[mt][nf] = (f32x4){0.f, 0.f, 0.f, 0.f};

#pragma unroll
        for (int ks = 0; ks < 8; ++ks) {
            bf16x8 b0 = *(const bf16x8*)(bp + (0 * 8 + ks) * 512);
            bf16x8 b1 = *(const bf16x8*)(bp + (1 * 8 + ks) * 512);
            bf16x8 b2 = *(const bf16x8*)(bp + (2 * 8 + ks) * 512);
            bf16x8 b3 = *(const bf16x8*)(bp + (3 * 8 + ks) * 512);
#pragma unroll
            for (int mt = 0; mt < MT; ++mt) {
                acc[mt][0] = __builtin_amdgcn_mfma_f32_16x16x32_bf16(a[mt][ks], b0, acc[mt][0], 0, 0, 0);
                acc[mt][1] = __builtin_amdgcn_mfma_f32_16x16x32_bf16(a[mt][ks], b1, acc[mt][1], 0, 0, 0);
                acc[mt][2] = __builtin_amdgcn_mfma_f32_16x16x32_bf16(a[mt][ks], b2, acc[mt][2], 0, 0, 0);
                acc[mt][3] = __builtin_amdgcn_mfma_f32_16x16x32_bf16(a[mt][ks], b3, acc[mt][3], 0, 0, 0);
            }
        }

        float bv[4] = {0.f, 0.f, 0.f, 0.f};
        if (HAS_BIAS) {
#pragma unroll
            for (int nf = 0; nf < 4; ++nf) bv[nf] = bias[nb + nf * 16 + c];
        }

        if (LSE_PARTIAL) {
#pragma unroll
            for (int mt = 0; mt < MT; ++mt)
#pragma unroll
                for (int r = 0; r < 4; ++r) {
                    float l0 = acc[mt][0][r] + bv[0];
                    float l1 = acc[mt][1][r] + bv[1];
                    float l2 = acc[mt][2][r] + bv[2];
                    float l3 = acc[mt][3][r] + bv[3];
                    float mc = fmaxf(fmaxf(l0, l1), fmaxf(l2, l3));
                    float mn = fmaxf(mrun[mt][r], mc);
                    srun[mt][r] = srun[mt][r] * __expf(mrun[mt][r] - mn)
                            + __expf(l0 - mn) + __expf(l1 - mn)
                            + __expf(l2 - mn) + __expf(l3 - mn);
                    mrun[mt][r] = mn;
                }
        }

        if (WRITE_C) {
            const int base = w * (16 * 68);
#pragma unroll
            for (int mt = 0; mt < MT; ++mt) {
                const int row16 = m0 + mt * 64 + w * 16;
#pragma unroll
                for (int nf = 0; nf < 4; ++nf)
#pragma unroll
                    for (int r = 0; r < 4; ++r) {
                        float v = acc[mt][nf][r] + bv[nf];
                        if (LSE_SUB) v -= lsev[mt][r];
                        lds_st[base + (4 * g + r) * 68 + nf * 16 + c] = v;
                    }
#pragma unroll
                for (int i = 0; i < 4; ++i) {
                    int lr = i * 4 + g;
                    float4 v = *(const float4*)&lds_st[base + lr * 68 + c * 4];
                    *(float4*)(C + (size_t)(row16 + lr) * ldc + nb + c * 4) = v;
                }
            }
        }
    }

    if (LSE_PARTIAL) {
#pragma unroll
        for (int mt = 0; mt < MT; ++mt)
#pragma unroll
            for (int r = 0; r < 4; ++r) {
                float m = mrun[mt][r], s = srun[mt][r];
#pragma unroll
                for (int mk = 1; mk <= 8; mk <<= 1) {
                    float m2 = __shfl_xor(m, mk);
                    float s2 = __shfl_xor(s, mk);
                    float mn = fmaxf(m, m2);
                    s = s * __expf(m - mn) + s2 * __expf(m2 - mn);
                    m = mn;
                }
                if (c == 0) {
                    int row = m0 + mt * 64 + w * 16 + 4 * g + r;
                    pm[(size_t)row * ntiles + blockIdx.y] = m;
                    ps[(size_t)row * ntiles + blockIdx.y] = s;
                }
            }
    }
}

// ============ LDS-staged GEMM (passes A/B): B via global_load_lds ============
// DBUF=true: double-buffered (64KB LDS, 2 blocks/CU) — pass A (no C write).
// DBUF=false: single-buffered (49KB LDS, 3 blocks/CU) — pass B (C write);
// cross-block overlap replaces the intra-block pipeline at higher occupancy.
template<bool DBUF, bool WRITE_C, bool HAS_BIAS, bool LSE_PARTIAL, bool LSE_SUB>
__global__ __launch_bounds__(256, 2) void gemm_ls(
    const __hip_bfloat16* __restrict__ A,
    const __hip_bfloat16* __restrict__ B,
    int ldc, int nchunks, int ntiles,
    const float* __restrict__ bias,
    const float* __restrict__ lse,
    float* __restrict__ C,
    float* __restrict__ pm, float* __restrict__ ps)
{
    __shared__ __align__(16) char ldsB[DBUF ? 2 : 1][32768];
    __shared__ float lds_st[WRITE_C ? (4 * 16 * 68) : 1];

    const int tid  = threadIdx.x;
    const int w    = tid >> 6;
    const int lane = tid & 63;
    const int g    = lane >> 4;
    const int c    = lane & 15;
    const int m0   = blockIdx.x * 128;
    const int n0   = blockIdx.y * (nchunks * 64);
    const int jb0  = n0 >> 4;

    bf16x8 a[2][8];
#pragma unroll
    for (int mt = 0; mt < 2; ++mt) {
        const int row16 = m0 + mt * 64 + w * 16;
        const __hip_bfloat16* ap = A + (((size_t)(row16 >> 4) * 8) * 64 + lane) * 8;
#pragma unroll
        for (int ks = 0; ks < 8; ++ks) a[mt][ks] = *(const bf16x8*)(ap + ks * 512);
    }

    float mrun[2][4], srun[2][4];
#pragma unroll
    for (int mt = 0; mt < 2; ++mt)
#pragma unroll
        for (int r = 0; r < 4; ++r) { mrun[mt][r] = -3.0e38f; srun[mt][r] = 0.f; }

    float lsev[2][4];
    if (LSE_SUB) {
#pragma unroll
        for (int mt = 0; mt < 2; ++mt)
#pragma unroll
            for (int r = 0; r < 4; ++r)
                lsev[mt][r] = lse[m0 + mt * 64 + w * 16 + 4 * g + r];
    }

    const char* Bbase = (const char*)B;
#define STAGE_TILE(bbuf, nc_)                                                     \
    {                                                                             \
        const char* src = Bbase + ((size_t)(jb0 + (nc_) * 4) * 8 * 64) * 16;      \
        _Pragma("unroll")                                                         \
        for (int i_ = 0; i_ < 8; ++i_) {                                          \
            int seg = w * 8 + i_;                                                 \
            gload_lds16(src + (size_t)seg * 1024 + lane * 16,                     \
                        &ldsB[bbuf][seg * 1024]);                                 \
        }                                                                         \
    }

    int buf = 0;
    if (DBUF) {
        STAGE_TILE(0, 0);
        __syncthreads();
    }

    for (int nc = 0; nc < nchunks; ++nc) {
        if (DBUF) {
            if (nc + 1 < nchunks) STAGE_TILE(buf ^ 1, nc + 1);
        } else {
            STAGE_TILE(0, nc);
            __syncthreads();   // stage complete
        }

        const int nb = n0 + nc * 64;
        f32x4 acc[2][4];
#pragma unroll
        for (int mt = 0; mt < 2; ++mt)
#pragma unroll
            for (int nf = 0; nf < 4; ++nf) acc[mt][nf] = (f32x4){0.f, 0.f, 0.f, 0.f};

#pragma unroll
        for (int ks = 0; ks < 8; ++ks) {
            bf16x8 b0 = *(const bf16x8*)&ldsB[buf][((0 * 8 + ks) * 64 + lane) * 16];
            bf16x8 b1 = *(const bf16x8*)&ldsB[buf][((1 * 8 + ks) * 64 + lane) * 16];
            bf16x8 b2 = *(const bf16x8*)&ldsB[buf][((2 * 8 + ks) * 64 + lane) * 16];
            bf16x8 b3 = *(const bf16x8*)&ldsB[buf][((3 * 8 + ks) * 64 + lane) * 16];
#pragma unroll
            for (int mt = 0; mt < 2; ++mt) {
                acc[mt][0] = __builtin_amdgcn_mfma_f32_16x16x32_bf16(a[mt][ks], b0, acc[mt][0], 0, 0, 0);
                acc[mt][1] = __builtin_amdgcn_mfma_f32_16x16x32_bf16(a[mt][ks], b1, acc[mt][1], 0, 0, 0);
                acc[mt][2] = __builtin_amdgcn_mfma_f32_16x16x32_bf16(a[mt][ks], b2, acc[mt][2], 0, 0, 0);
                acc[mt][3] = __builtin_amdgcn_mfma_f32_16x16x32_bf16(a[mt][ks], b3, acc[mt][3], 0, 0, 0);
            }
        }

        float bv[4] = {0.f, 0.f, 0.f, 0.f};
        if (HAS_BIAS) {
#pragma unroll
            for (int nf = 0; nf < 4; ++nf) bv[nf] = bias[nb + nf * 16 + c];
        }

        if (LSE_PARTIAL) {
#pragma unroll
            for (int mt = 0; mt < 2; ++mt)
#pragma unroll
                for (int r = 0; r < 4; ++r) {
                    float l0 = acc[mt][0][r] + bv[0];
                    float l1 = acc[mt][1][r] + bv[1];
                    float l2 = acc[mt][2][r] + bv[2];
                    float l3 = acc[mt][3][r] + bv[3];
                    float mc = fmaxf(fmaxf(l0, l1), fmaxf(l2, l3));
                    float mn = fmaxf(mrun[mt][r], mc);
                    srun[mt][r] = srun[mt][r] * __expf(mrun[mt][r] - mn)
                            + __expf(l0 - mn) + __expf(l1 - mn)
                            + __expf(l2 - mn) + __expf(l3 - mn);
                    mrun[mt][r] = mn;
                }
        }

        if (WRITE_C) {
            const int base = w * (16 * 68);
#pragma unroll
            for (int mt = 0; mt < 2; ++mt) {
                const int row16 = m0 + mt * 64 + w * 16;
#pragma unroll
                for (int nf = 0; nf < 4; ++nf)
#pragma unroll
                    for (int r = 0; r < 4; ++r) {
                        float v = acc[mt][nf][r] + bv[nf];
                        if (LSE_SUB) v -= lsev[mt][r];
                        lds_st[base + (4 * g + r) * 68 + nf * 16 + c] = v;
                    }
                // wave-private restage: no barrier needed
#pragma unroll
                for (int i = 0; i < 4; ++i) {
                    int lr = i * 4 + g;
                    float4 v = *(const float4*)&lds_st[base + lr * 68 + c * 4];
                    *(float4*)(C + (size_t)(row16 + lr) * ldc + nb + c * 4) = v;
                }
            }
        }

        __syncthreads();   // DBUF: drains vmcnt + buf reuse; else: reads done before overwrite
        if (DBUF) buf ^= 1;
    }
#undef STAGE_TILE

    if (LSE_PARTIAL) {
#pragma unroll
        for (int mt = 0; mt < 2; ++mt)
#pragma unroll
            for (int r = 0; r < 4; ++r) {
                float m = mrun[mt][r], s = srun[mt][r];
#pragma unroll
                for (int mk = 1; mk <= 8; mk <<= 1) {
                    float m2 = __shfl_xor(m, mk);
                    float s2 = __shfl_xor(s, mk);
                    float mn = fmaxf(m, m2);
                    s = s * __expf(m - mn) + s2 * __expf(m2 - mn);
                    m = mn;
                }
                if (c == 0) {
                    int row = m0 + mt * 64 + w * 16 + 4 * g + r;
                    pm[(size_t)row * ntiles + blockIdx.y] = m;
                    ps[(size_t)row * ntiles + blockIdx.y] = s;
                }
            }
    }
}

// ============ fused recurrence v6 + piggybacked W_out pack on extra blocks ============
// Blocks [0,16): proven v6 rnn. Blocks [16, 16+NPACK): pack one 512-chunk slice
// of W_out into Wp and exit (rides the CUs left idle by the 16-block rnn).
// Liveness-safe: pack blocks terminate unconditionally, so delayed rnn blocks
// always become schedulable (no dispatch-order dependence).
__global__ __launch_bounds__(512) void rnn_fused6(
    const unsigned char* __restrict__ ecan,
    const float* __restrict__ gi,          // [4096][3072]
    const _Float16* __restrict__ Wr,       // [4 slots][8 j8][6 tt][8 ks][64][8]
    const float* __restrict__ ecbih, const float* __restrict__ ecbhh,
    const float* __restrict__ esbih, const float* __restrict__ esbhh,
    const float* __restrict__ dcbih, const float* __restrict__ dcbhh,
    const float* __restrict__ dsbih, const float* __restrict__ dsbhh,
    const float* __restrict__ WmT, const float* __restrict__ WlT,
    const float* __restrict__ WhT,
    const float* __restrict__ b_mean, const float* __restrict__ b_logv,
    const float* __restrict__ b_l2h,
    const float* __restrict__ enc_init, const float* __restrict__ eps,
    float* __restrict__ out_mean, float* __restrict__ out_logv,
    float* __restrict__ out_z,
    __hip_bfloat16* __restrict__ outs_pk,
    _Float16* __restrict__ xh,             // [65][128][256] f16, write-once slots
    int* __restrict__ flags,               // [16]
    const float* __restrict__ W_out, __hip_bfloat16* __restrict__ Wp)
{
    __shared__ _Float16 wlds[6 * 8 * 64 * 8];   // 48K
    __shared__ _Float16 hpk[64 * 64 * 8];       // 64K, A-frag layout of h
    __shared__ _Float16 ghl[DD * GHLP];         // 25K: gh tile [128][96+pad]
    __shared__ float    bsum[4 * 256];          // 4K: br,bz,bin,bhn
    __shared__ unsigned char ecan_l[TT * DD];   // 4K

    const int tid = threadIdx.x;

    if (blockIdx.x >= NBLK) {
        // ---- W_out pack slice: 512 chunks (1,024,000 total over NPACK blocks) ----
        int i = (blockIdx.x - NBLK) * 512 + tid;
        if (i < 2000 * 8 * 64) {
            int lane = i & 63, ks = (i >> 6) & 7, j = i >> 9;
            int g2 = lane >> 4, c2 = lane & 15;
            const float* s = W_out + (size_t)(j * 16 + c2) * HH + ks * 32 + g2 * 8;
            float4 v0 = *(const float4*)s;
            float4 v1 = *(const float4*)(s + 4);
            bf16x8 o;
            o[0] = (short)f2bf(v0.x); o[1] = (short)f2bf(v0.y);
            o[2] = (short)f2bf(v0.z); o[3] = (short)f2bf(v0.w);
            o[4] = (short)f2bf(v1.x); o[5] = (short)f2bf(v1.y);
            o[6] = (short)f2bf(v1.z); o[7] = (short)f2bf(v1.w);
            *(bf16x8*)(Wp + (size_t)i * 8) = o;
        }
        return;
    }

    const int v   = blockIdx.x & 1;             // 0: child (e!=0), 1: sibling
    const int j8  = blockIdx.x >> 1;
    const int w    = tid >> 6;
    const int lane = tid & 63;
    const int g    = lane >> 4;
    const int c    = lane & 15;
    const int dq   = w & 3;
    const int jg2  = w >> 2;

    for (int u = tid; u < TT * DD; u += 512) ecan_l[u] = ecan[u];

    // ---- init hpk from enc_init ----
    for (int u = tid; u < 4096; u += 512) {
        int chunk = u >> 6, ln = u & 63;
        int dt = chunk >> 3, ks = chunk & 7, lg = ln >> 4, lc = ln & 15;
        const float* s = enc_init + (size_t)(dt * 16 + lc) * HH + ks * 32 + lg * 8;
        float4 v0 = *(const float4*)s;
        float4 v1 = *(const float4*)(s + 4);
        f16x8 o;
        o[0] = (_Float16)v0.x; o[1] = (_Float16)v0.y;
        o[2] = (_Float16)v0.z; o[3] = (_Float16)v0.w;
        o[4] = (_Float16)v1.x; o[5] = (_Float16)v1.y;
        o[6] = (_Float16)v1.z; o[7] = (_Float16)v1.w;
        *(f16x8*)&hpk[(size_t)u * 8] = o;
    }
    __syncthreads();

    int bi = 0;   // barrier index == xh slot

    for (int p = 0; p < 2; ++p) {
        // ---- weights + biases into LDS, once per phase ----
        {
            const _Float16* wsrc = Wr + ((size_t)(p * 2 + v) * 8 + j8) * (3072 * 8);
            for (int idx = tid; idx < 3072; idx += 512)
                *(f16x8*)&wlds[(size_t)idx * 8] = *(const f16x8*)(wsrc + (size_t)idx * 8);
        }
        {
            const float* bih = p ? (v ? dsbih : dcbih) : (v ? esbih : ecbih);
            const float* bhh = p ? (v ? dsbhh : dcbhh) : (v ? esbhh : ecbhh);
            if (tid < 256) {
                bsum[tid]       = bih[tid]       + bhh[tid];
                bsum[256 + tid] = bih[256 + tid] + bhh[256 + tid];
                bsum[512 + tid] = bih[512 + tid];
                bsum[768 + tid] = bhh[512 + tid];
            }
        }
        __syncthreads();

        for (int st = 0; st < TT; ++st) {
            // ---- gi prefetch for this step's gate units ----
            f32x4 gpr0[3], gpr1[3];
            bool sel0, sel1;
            {
                const int u0 = tid, u1 = tid + 512;
                const int d0 = u0 >> 3, d1 = u1 >> 3;
                const int jgA = j8 * 32 + (u0 & 7) * 4;
                const int jgB = j8 * 32 + (u1 & 7) * 4;
                sel0 = (ecan_l[st * DD + d0] != 0) == (v == 0);
                sel1 = (ecan_l[st * DD + d1] != 0) == (v == 0);
                if (sel0) {
                    const float* gp = gi + (size_t)(st * DD + d0) * 3072 + p * 1536 + v * 768 + jgA;
                    gpr0[0] = *(const f32x4*)gp;
                    gpr0[1] = *(const f32x4*)(gp + 256);
                    gpr0[2] = *(const f32x4*)(gp + 512);
                }
                if (sel1) {
                    const float* gp = gi + (size_t)(st * DD + d1) * 3072 + p * 1536 + v * 768 + jgB;
                    gpr1[0] = *(const f32x4*)gp;
                    gpr1[1] = *(const f32x4*)(gp + 256);
                    gpr1[2] = *(const f32x4*)(gp + 512);
                }
            }

            // ---- MFMA: acc[dti][gate] from LDS h x LDS W ----
            f32x4 acc[2][3];
#pragma unroll
            for (int a = 0; a < 2; ++a)
#pragma unroll
                for (int b = 0; b < 3; ++b) acc[a][b] = (f32x4){0.f, 0.f, 0.f, 0.f};
#pragma unroll
            for (int ks = 0; ks < 8; ++ks) {
                f16x8 a0 = *(const f16x8*)&hpk[(((dq * 2 + 0) * 8 + ks) * 64 + lane) * 8];
                f16x8 a1 = *(const f16x8*)&hpk[(((dq * 2 + 1) * 8 + ks) * 64 + lane) * 8];
#pragma unroll
                for (int gt = 0; gt < 3; ++gt) {
                    f16x8 bf = *(const f16x8*)&wlds[(((jg2 * 3 + gt) * 8 + ks) * 64 + lane) * 8];
                    acc[0][gt] = __builtin_amdgcn_mfma_f32_16x16x32_f16(a0, bf, acc[0][gt], 0, 0, 0);
                    acc[1][gt] = __builtin_amdgcn_mfma_f32_16x16x32_f16(a1, bf, acc[1][gt], 0, 0, 0);
                }
            }

            // ---- acc -> ghl (f16) ----
#pragma unroll
            for (int dti = 0; dti < 2; ++dti) {
                const int dt = dq * 2 + dti;
#pragma unroll
                for (int gt = 0; gt < 3; ++gt)
#pragma unroll
                    for (int rr = 0; rr < 4; ++rr)
                        ghl[(dt * 16 + 4 * g + rr) * GHLP + gt * 32 + jg2 * 16 + c] =
                            (_Float16)acc[dti][gt][rr];
            }
            __syncthreads();

            // ---- gate: 2 units/thread, unit = (d, 4 consecutive j) ----
            _Float16* xcur = xh + (size_t)bi * (DD * HH);
#pragma unroll
            for (int uu = 0; uu < 2; ++uu) {
                const bool sel = uu ? sel1 : sel0;
                if (!sel) continue;
                const int u = tid + uu * 512;
                const int d = u >> 3, jq = u & 7;
                const int jl = jq * 4;
                const int jg_ = j8 * 32 + jl;
                const f32x4* gpr = uu ? gpr1 : gpr0;

                f32x4 br  = *(const f32x4*)&bsum[jg_];
                f32x4 bz  = *(const f32x4*)&bsum[256 + jg_];
                f32x4 bni = *(const f32x4*)&bsum[512 + jg_];
                f32x4 bnh = *(const f32x4*)&bsum[768 + jg_];
                const _Float16* gd = &ghl[d * GHLP];
                const int dt = d >> 4, lc = d & 15, ks = jg_ >> 5, lg = (jg_ >> 3) & 3;
                const int ch = ((dt * 8 + ks) * 64 + lg * 16 + lc);
                const _Float16* hop = &hpk[(size_t)ch * 8 + (jg_ & 7)];

                _Float16 hn[4];
                unsigned short ob[4];
#pragma unroll
                for (int m = 0; m < 4; ++m) {
                    float ghr = (float)gd[jl + m];
                    float ghz = (float)gd[32 + jl + m];
                    float ghn = (float)gd[64 + jl + m];
                    float rg = 1.f / (1.f + __expf(-(gpr[0][m] + br[m] + ghr)));
                    float zg = 1.f / (1.f + __expf(-(gpr[1][m] + bz[m] + ghz)));
                    float nn = tanhf(gpr[2][m] + bni[m] + rg * (ghn + bnh[m]));
                    float hv = (1.f - zg) * nn + zg * (float)hop[m];
                    hn[m] = (_Float16)hv;
                    ob[m] = f2bf(hv);
                }
                __hip_atomic_store((unsigned long long*)(xcur + (size_t)d * HH + jg_),
                                   pack4h(hn[0], hn[1], hn[2], hn[3]),
                                   __ATOMIC_RELAXED, __HIP_MEMORY_SCOPE_AGENT);
                if (p) {
                    union { unsigned short s[4]; unsigned long long u; } ou;
                    ou.s[0] = ob[0]; ou.s[1] = ob[1]; ou.s[2] = ob[2]; ou.s[3] = ob[3];
                    size_t och = ((size_t)(st * 8 + dt) * 8 + ks) * 64 + lg * 16 + lc;
                    *(unsigned long long*)((unsigned short*)outs_pk + och * 8 + (jg_ & 7)) = ou.u;
                }
            }
            __syncthreads();   // drains all waves' stores

            // ---- flag barrier ----
            if (tid == 0)
                __hip_atomic_store(&flags[blockIdx.x], bi + 1,
                                   __ATOMIC_RELAXED, __HIP_MEMORY_SCOPE_AGENT);
            if (tid < 64) {
                for (;;) {
                    int f = (tid < NBLK)
                          ? __hip_atomic_load(&flags[tid], __ATOMIC_RELAXED, __HIP_MEMORY_SCOPE_AGENT)
                          : 0x7fffffff;
                    if (__all(f >= bi + 1)) break;
                    __builtin_amdgcn_s_sleep(1);
                }
            }
            __syncthreads();

            // ---- staging: batched 8x16B loads -> hpk ----
            {
                const _Float16* xr = xh + (size_t)bi * (DD * HH);
                f16x8 tv[8];
#pragma unroll
                for (int i = 0; i < 8; ++i) {
                    int u = tid + i * 512;
                    int chunk = u >> 6, ln = u & 63;
                    int dt = chunk >> 3, ks = chunk & 7, lg = ln >> 4, lc = ln & 15;
                    tv[i] = *(const f16x8*)(xr + (size_t)(dt * 16 + lc) * HH + ks * 32 + lg * 8);
                }
#pragma unroll
                for (int i = 0; i < 8; ++i)
                    *(f16x8*)&hpk[(size_t)(tid + i * 512) * 8] = tv[i];
            }
            __syncthreads();
            ++bi;
        }

        if (p == 0) {
            // ---- latent head, d-sharded (8 rows per block) ----
            float* hlin = (float*)ghl;          // reuse ghl (needs 8KB)
            const int d8 = tid >> 6;
            const int q  = tid & 63;
            const int dg = blockIdx.x * 8 + d8;
            for (int u = tid; u < 2048; u += 512) {
                int du = u >> 8, k = u & 255;
                int d = blockIdx.x * 8 + du;
                hlin[du * 256 + k] = (float)hpk[(((size_t)(d >> 4) * 8 + (k >> 5)) * 64
                                      + ((k >> 3) & 3) * 16 + (d & 15)) * 8 + (k & 7)];
            }
            __syncthreads();
            f32x4 mean4, logv4;
            {
                f32x4 sm = {0, 0, 0, 0}, sl = {0, 0, 0, 0};
                const float* hl = hlin + d8 * 256;
                for (int k = 0; k < HH; ++k) {
                    float hv = hl[k];
                    sm += hv * *(const f32x4*)(WmT + (size_t)k * 256 + q * 4);
                    sl += hv * *(const f32x4*)(WlT + (size_t)k * 256 + q * 4);
                }
                mean4 = sm + *(const f32x4*)(b_mean + q * 4);
                logv4 = sl + *(const f32x4*)(b_logv + q * 4);
                *(f32x4*)(out_mean + (size_t)dg * ZZ + q * 4) = mean4;
                *(f32x4*)(out_logv + (size_t)dg * ZZ + q * 4) = logv4;
            }
            __syncthreads();
            {
                f32x4 ep = *(const f32x4*)(eps + (size_t)dg * ZZ + q * 4);
                f32x4 zv;
#pragma unroll
                for (int m = 0; m < 4; ++m)
                    zv[m] = ep[m] * __expf(0.5f * logv4[m]) + mean4[m];
                *(f32x4*)(out_z + (size_t)dg * ZZ + q * 4) = zv;
                *(f32x4*)(hlin + d8 * 256 + q * 4) = zv;
            }
            __syncthreads();
            {
                f32x4 s = {0, 0, 0, 0};
                const float* zlp = hlin + d8 * 256;
                for (int k = 0; k < ZZ; ++k)
                    s += zlp[k] * *(const f32x4*)(WhT + (size_t)k * 256 + q * 4);
                f32x4 h0v = s + *(const f32x4*)(b_l2h + q * 4);
                __hip_atomic_store(
                    (unsigned long long*)(xh + (size_t)bi * (DD * HH) + (size_t)dg * HH + q * 4),
                    pack4h((_Float16)h0v[0], (_Float16)h0v[1],
                           (_Float16)h0v[2], (_Float16)h0v[3]),
                    __ATOMIC_RELAXED, __HIP_MEMORY_SCOPE_AGENT);
            }
            __syncthreads();
            if (tid == 0)
                __hip_atomic_store(&flags[blockIdx.x], bi + 1,
                                   __ATOMIC_RELAXED, __HIP_MEMORY_SCOPE_AGENT);
            if (tid < 64) {
                for (;;) {
                    int f = (tid < NBLK)
                          ? __hip_atomic_load(&flags[tid], __ATOMIC_RELAXED, __HIP_MEMORY_SCOPE_AGENT)
                          : 0x7fffffff;
                    if (__all(f >= bi + 1)) break;
                    __builtin_amdgcn_s_sleep(1);
                }
            }
            __syncthreads();
            {
                const _Float16* xr = xh + (size_t)bi * (DD * HH);
                f16x8 tv[8];
#pragma unroll
                for (int i = 0; i < 8; ++i) {
                    int u = tid + i * 512;
                    int chunk = u >> 6, ln = u & 63;
                    int dt = chunk >> 3, ks = chunk & 7, lg = ln >> 4, lc = ln & 15;
                    tv[i] = *(const f16x8*)(xr + (size_t)(dt * 16 + lc) * HH + ks * 32 + lg * 8);
                }
#pragma unroll
                for (int i = 0; i < 8; ++i)
                    *(f16x8*)&hpk[(size_t)(tid + i * 512) * 8] = tv[i];
            }
            __syncthreads();
            ++bi;
        }
    }
}

// ---------------- per-row logsumexp merge (one wave per row, nt <= 64) ----------------
__global__ __launch_bounds__(64) void lse_reduce(
    const float* __restrict__ pm, const float* __restrict__ ps,
    float* __restrict__ lse, int nt)
{
    int row = blockIdx.x;
    int l = threadIdx.x;
    float m = (l < nt) ? pm[(size_t)row * nt + l] : -3.0e38f;
    float s = (l < nt) ? ps[(size_t)row * nt + l] : 0.f;
    for (int mk = 1; mk <= 32; mk <<= 1) {
        float m2 = __shfl_xor(m, mk);
        float s2 = __shfl_xor(s, mk);
        float mn = fmaxf(m, m2);
        s = s * __expf(m - mn) + s2 * __expf(m2 - mn);
        m = mn;
    }
    if (l == 0) lse[row] = m + logf(s);
}

extern "C" void kernel_launch(void* const* d_in, const int* in_sizes, int n_in,
                              void* d_out, int out_size, void* d_ws, size_t ws_size,
                              hipStream_t stream)
{
    const int*           nodes     = (const int*)d_in[0];
    const unsigned char* edges_raw = (const unsigned char*)d_in[1];
    const float* emb    = (const float*)d_in[2];
    const float* ecWih  = (const float*)d_in[3];
    const float* ecWhh  = (const float*)d_in[4];
    const float* ecbih  = (const float*)d_in[5];
    const float* ecbhh  = (const float*)d_in[6];
    const float* esWih  = (const float*)d_in[7];
    const float* esWhh  = (const float*)d_in[8];
    const float* esbih  = (const float*)d_in[9];
    const float* esbhh  = (const float*)d_in[10];
    const float* dcWih  = (const float*)d_in[11];
    const float* dcWhh  = (const float*)d_in[12];
    const float* dcbih  = (const float*)d_in[13];
    const float* dcbhh  = (const float*)d_in[14];
    const float* dsWih  = (const float*)d_in[15];
    const float* dsWhh  = (const float*)d_in[16];
    const float* dsbih  = (const float*)d_in[17];
    const float* dsbhh  = (const float*)d_in[18];
    const float* W_mean = (const float*)d_in[19];
    const float* b_mean = (const float*)d_in[20];
    const float* W_logv = (const float*)d_in[21];
    const float* b_logv = (const float*)d_in[22];
    const float* W_l2h  = (const float*)d_in[23];
    const float* b_l2h  = (const float*)d_in[24];
    const float* W_out  = (const float*)d_in[25];
    const float* b_out  = (const float*)d_in[26];
    const float* enc_init = (const float*)d_in[27];
    const float* eps    = (const float*)d_in[28];

    float* out      = (float*)d_out;
    float* out_mean = out + (size_t)TT * DD * VV;
    float* out_logv = out_mean + DD * ZZ;
    float* out_z    = out_logv + DD * ZZ;
    float* gi       = out;                  // scratch in logits region: [4096][3072]

    char* ws = (char*)d_ws;
    __hip_bfloat16* outs_pk = (__hip_bfloat16*)(ws + 0);         // 2MB
    __hip_bfloat16* Ap      = (__hip_bfloat16*)(ws + 2097152);   // 2MB
    __hip_bfloat16* Wp      = (__hip_bfloat16*)(ws + 4194304);   // 16.4MB
    __hip_bfloat16* Bp_all  = (__hip_bfloat16*)(ws + 20971520);  // 1.5MB
    _Float16*       Wr      = (_Float16*)(ws + 22544384);        // 1.5MB rnn-frag Whh x4
    float*          WmT     = (float*)(ws + 24117248);           // 256KB (x3 contiguous)
    float*          pm      = (float*)(ws + 24903680);           // 800KB
    float*          ps      = (float*)(ws + 25722880);           // 800KB
    float*          lse     = (float*)(ws + 26542080);           // 16KB
    unsigned char*  ecan    = (unsigned char*)(ws + 26558464);   // 4KB
    _Float16*       xh      = (_Float16*)(ws + 26562560);        // 65 x 64KB
    int*            flags   = (int*)(ws + 30822400);             // 64B
    float*          WlT     = WmT + 65536;
    float*          WhT     = WmT + 131072;

    hipMemsetAsync(flags, 0, 64, stream);

    edge_canon_k<<<1, 256, 0, stream>>>(edges_raw, ecan);
    pack_frag4<<<dim3(96, 4), 256, 0, stream>>>(ecWih, esWih, dcWih, dsWih, Bp_all);
    pack_wrnn4<<<dim3(96, 4), 256, 0, stream>>>(ecWhh, esWhh, dcWhh, dsWhh, Wr);
    pack_lat3<<<dim3(256, 3), 256, 0, stream>>>(W_mean, W_logv, W_l2h, WmT);
    gather_pack<<<512, 256, 0, stream>>>(nodes, emb, Ap);

    // gi[4096][3072] = emb-gather x [all 4 W_ih]^T  (into d_out scratch)
    gemm_rs<2, true, false, false, false><<<dim3(32, 6), 256, 0, stream>>>(
        Ap, Bp_all, 3072, 8, 6, nullptr, nullptr, gi, nullptr, nullptr);

    // fused recurrence (+ W_out pack on idle CUs)
    rnn_fused6<<<NBLK + NPACK, 512, 0, stream>>>(
        ecan, gi, Wr,
        ecbih, ecbhh, esbih, esbhh, dcbih, dcbhh, dsbih, dsbhh,
        WmT, WlT, WhT, b_mean, b_logv, b_l2h,
        enc_init, eps, out_mean, out_logv, out_z, outs_pk, xh, flags,
        W_out, Wp);

    // pass A: LSE partials only (dbuf LDS-staged B, no C write)
    gemm_ls<true, false, true, true, false><<<dim3(32, NTL), 256, 0, stream>>>(
        outs_pk, Wp, VV, 10, NTL, b_out, nullptr, nullptr, pm, ps);
    lse_reduce<<<4096, 64, 0, stream>>>(pm, ps, lse, NTL);
    // pass B: recompute, write logp = logits - lse (single-buf staging, 3 blocks/CU)
    gemm_ls<false, true, true, false, true><<<dim3(32, NTL), 256, 0, stream>>>(
        outs_pk, Wp, VV, 10, NTL, b_out, lse, out, nullptr, nullptr);
}